// Round 11
// baseline (429.379 us; speedup 1.0000x reference)
//
#include <hip/hip_runtime.h>
#include <math.h>

#define BB    2
#define NN    2048
#define CDIM  1024
#define HEADS 16
#define HDIM  64
#define MLPD  4096
#define MODC  6144
#define EPSV  1e-5f
#define LOG2E 1.4426950408889634f
#define MSPLIT 16

typedef __attribute__((ext_vector_type(8))) short s8v;     // 8 bf16 (4 VGPRs)
typedef __attribute__((ext_vector_type(4))) float f4v;     // MFMA C/D

__device__ inline unsigned short f2bf(float f) {
  union { float f; unsigned u; } v; v.f = f;
  unsigned r = v.u + 0x7FFFu + ((v.u >> 16) & 1u);   // RNE
  return (unsigned short)(r >> 16);
}
__device__ inline float bf2f(unsigned short h) {
  union { unsigned u; float f; } v; v.u = ((unsigned)h) << 16;
  return v.f;
}

// DPP 16-lane max reduce: VALU-only (no ds_swizzle -> keeps the DS pipe free).
template<int CTRL>
__device__ __forceinline__ float dpp_max_step(float v) {
  int iv = __float_as_int(v);
  int sh = __builtin_amdgcn_update_dpp(iv, iv, CTRL, 0xF, 0xF, false);
  return fmaxf(v, __int_as_float(sh));
}
__device__ __forceinline__ float max16(float v) {
  v = dpp_max_step<0xB1>(v);    // quad_perm [1,0,3,2]  (xor 1)
  v = dpp_max_step<0x4E>(v);    // quad_perm [2,3,0,1]  (xor 2)
  v = dpp_max_step<0x124>(v);   // row_ror:4
  v = dpp_max_step<0x128>(v);   // row_ror:8
  return v;
}

// ---------------------------------------------------------------------------
// K1a: split-K partials for mod = silu(t_emb) @ ada_W
// ---------------------------------------------------------------------------
__global__ __launch_bounds__(256) void mod_part(
    const float* __restrict__ t_emb, const float* __restrict__ ada_W,
    float* __restrict__ part) {
  int j = blockIdx.x * 256 + threadIdx.x;
  int b = blockIdx.y, ks = blockIdx.z;
  __shared__ float st[64];
  if (threadIdx.x < 64) {
    float v = t_emb[b * CDIM + ks * 64 + threadIdx.x];
    st[threadIdx.x] = v / (1.0f + expf(-v));
  }
  __syncthreads();
  float acc = 0.f;
  const float* wp = ada_W + (size_t)(ks * 64) * MODC + j;
  #pragma unroll 8
  for (int i = 0; i < 64; ++i) acc += st[i] * wp[(size_t)i * MODC];
  part[((size_t)ks * BB + b) * MODC + j] = acc;
}

// K1b: reduce partials + bias
__global__ __launch_bounds__(256) void mod_reduce(
    const float* __restrict__ part, const float* __restrict__ ada_b,
    float* __restrict__ mod) {
  int idx = blockIdx.x * 256 + threadIdx.x;   // 0 .. B*MODC-1
  int b = idx / MODC, j = idx % MODC;
  float a = ada_b[j];
  #pragma unroll
  for (int s = 0; s < MSPLIT; ++s) a += part[((size_t)s * BB + b) * MODC + j];
  mod[(size_t)b * MODC + j] = a;
}

// ---------------------------------------------------------------------------
// K2: LN + adaLN modulation, bf16 output
// ---------------------------------------------------------------------------
__device__ inline float wave_sum64(float v) {
  for (int o = 32; o > 0; o >>= 1) v += __shfl_down(v, o, 64);
  return v;
}

__global__ __launch_bounds__(256) void ln_mod_bf16(
    const float* __restrict__ x, const float* __restrict__ g,
    const float* __restrict__ bta, const float* __restrict__ mod,
    int shift_off, int scale_off, unsigned short* __restrict__ out) {
  int r = blockIdx.x;
  int b = r / NN;
  int t = threadIdx.x;
  const float* xr = x + (size_t)r * CDIM;
  float4 xv = ((const float4*)xr)[t];
  float s  = xv.x + xv.y + xv.z + xv.w;
  float s2 = xv.x*xv.x + xv.y*xv.y + xv.z*xv.z + xv.w*xv.w;
  __shared__ float ws1[4], ws2[4];
  float sw = wave_sum64(s), s2w = wave_sum64(s2);
  int lane = t & 63, wid = t >> 6;
  if (lane == 0) { ws1[wid] = sw; ws2[wid] = s2w; }
  __syncthreads();
  float mu  = (ws1[0] + ws1[1] + ws1[2] + ws1[3]) * (1.0f / CDIM);
  float var = (ws2[0] + ws2[1] + ws2[2] + ws2[3]) * (1.0f / CDIM) - mu * mu;
  float rstd = rsqrtf(var + EPSV);
  const float* mods = mod + (size_t)b * MODC;
  float4 gv = ((const float4*)g)[t];
  float4 bv = ((const float4*)bta)[t];
  float4 sc = ((const float4*)(mods + scale_off))[t];
  float4 sh = ((const float4*)(mods + shift_off))[t];
  ushort4 ov;
  ov.x = f2bf(((xv.x - mu) * rstd * gv.x + bv.x) * (1.0f + sc.x) + sh.x);
  ov.y = f2bf(((xv.y - mu) * rstd * gv.y + bv.y) * (1.0f + sc.y) + sh.y);
  ov.z = f2bf(((xv.z - mu) * rstd * gv.z + bv.z) * (1.0f + sc.z) + sh.z);
  ov.w = f2bf(((xv.w - mu) * rstd * gv.w + bv.w) * (1.0f + sc.w) + sh.w);
  ((ushort4*)(out + (size_t)r * CDIM))[t] = ov;
}

// ---------------------------------------------------------------------------
// K3: ALL weight transpose-casts in one launch.  W[K][N] f32 -> Wt[N][K] bf16
// ---------------------------------------------------------------------------
__global__ __launch_bounds__(256) void wcast_all(
    const float* __restrict__ Wq, const float* __restrict__ Wk,
    const float* __restrict__ Wv, const float* __restrict__ Wo,
    const float* __restrict__ W1, const float* __restrict__ W2,
    unsigned short* __restrict__ Wqkvt, unsigned short* __restrict__ Wot,
    unsigned short* __restrict__ W1t, unsigned short* __restrict__ W2t) {
  int bid = blockIdx.x;
  const float* W; unsigned short* Wt; int K, N, t;
  if (bid < 4096) {
    int m = bid >> 10;
    t = bid & 1023;
    K = CDIM; N = CDIM;
    W  = (m == 0) ? Wq : (m == 1) ? Wk : (m == 2) ? Wv : Wo;
    Wt = (m == 3) ? Wot : (Wqkvt + (size_t)m * CDIM * CDIM);
  } else if (bid < 8192) {
    t = bid - 4096; K = CDIM; N = MLPD; W = W1; Wt = W1t;
  } else {
    t = bid - 8192; K = MLPD; N = CDIM; W = W2; Wt = W2t;
  }
  int ntiles = N >> 5;
  int n0 = (t % ntiles) * 32, k0 = (t / ntiles) * 32;
  __shared__ float tile[32][33];
  int tx = threadIdx.x & 31, ty = threadIdx.x >> 5;
  #pragma unroll
  for (int p = 0; p < 4; ++p)
    tile[ty + p * 8][tx] = W[(size_t)(k0 + ty + p * 8) * N + n0 + tx];
  __syncthreads();
  #pragma unroll
  for (int p = 0; p < 4; ++p)
    Wt[(size_t)(n0 + ty + p * 8) * K + k0 + tx] = f2bf(tile[tx][ty + p * 8]);
}

// ---------------------------------------------------------------------------
// K4 v3: bf16 MFMA GEMM, 128x128 tile, 1024 threads = 16 waves, intra-block
// K-split.  Epilogues: mode 0 = QKV 3-way split; mode 1 = exact GELU bf16.
// ---------------------------------------------------------------------------
__global__ __launch_bounds__(1024) void mfma_gemm_big(
    const unsigned short* __restrict__ A,
    const unsigned short* __restrict__ Bt,
    int M, int N, int K,
    unsigned short* __restrict__ Ob, unsigned short* __restrict__ Ob2,
    unsigned short* __restrict__ Ob3, int mode) {
  __shared__ unsigned short SH[3 * 16384];   // 3 bufs x (A 16KB + B 16KB) = 96 KB
  int tid = threadIdx.x;
  int wave = tid >> 6, lane = tid & 63;
  int quad = lane >> 4, l15 = lane & 15;
  int m0 = blockIdx.y * 128, n0 = blockIdx.x * 128;
  int pos = wave & 7;
  int om = pos >> 1, on = pos & 1;   // 32-row x 64-col output sub-tile
  int ks = wave >> 3;                // K-half (32 of 64) of the outer tile

  f4v acc[2][4] = {};

  int srow = lane >> 3;
  int ksrc = ((lane & 7) ^ (lane >> 3)) << 3;   // source k offset (elems)
  const int nt = K >> 6;

  #define STAGE_BIG(T, BUF)                                                    \
    {                                                                          \
      int k0_ = (T) << 6;                                                      \
      unsigned short* dsta = SH + (BUF) * 16384 + wave * 512;                  \
      const unsigned short* ga =                                               \
          A + (size_t)(m0 + 8 * wave + srow) * K + k0_ + ksrc;                 \
      __builtin_amdgcn_global_load_lds(                                        \
          (const __attribute__((address_space(1))) unsigned int*)(const void*)ga, \
          (__attribute__((address_space(3))) unsigned int*)(void*)dsta,        \
          16, 0, 0);                                                           \
      const unsigned short* gb =                                               \
          Bt + (size_t)(n0 + 8 * wave + srow) * K + k0_ + ksrc;                \
      __builtin_amdgcn_global_load_lds(                                        \
          (const __attribute__((address_space(1))) unsigned int*)(const void*)gb, \
          (__attribute__((address_space(3))) unsigned int*)(void*)(dsta + 8192), \
          16, 0, 0);                                                           \
    }

  STAGE_BIG(0, 0);
  STAGE_BIG(1, 1);
  asm volatile("s_waitcnt vmcnt(2)" ::: "memory");   // tile 0 landed
  __syncthreads();

  int kx = (ks * 32 + quad * 8) ^ ((l15 & 7) << 3);

  int rbuf = 0, sbuf = 2;
  for (int t = 0; t < nt; ++t) {
    if (t + 2 < nt) STAGE_BIG(t + 2, sbuf);

    const unsigned short* base = SH + rbuf * 16384;
    s8v af[2], bf[4];
    #pragma unroll
    for (int i = 0; i < 2; ++i)
      af[i] = *(const s8v*)(base + (om * 32 + i * 16 + l15) * 64 + kx);
    #pragma unroll
    for (int j = 0; j < 4; ++j)
      bf[j] = *(const s8v*)(base + 8192 + (on * 64 + j * 16 + l15) * 64 + kx);
    #pragma unroll
    for (int i = 0; i < 2; ++i)
      #pragma unroll
      for (int j = 0; j < 4; ++j)
        acc[i][j] = __builtin_amdgcn_mfma_f32_16x16x32_bf16(
            af[i], bf[j], acc[i][j], 0, 0, 0);

    if (t + 2 < nt) {
      asm volatile("s_waitcnt vmcnt(2)" ::: "memory");   // tile t+1 landed
    } else if (t + 1 < nt) {
      asm volatile("s_waitcnt vmcnt(0)" ::: "memory");
    }
    __syncthreads();
    rbuf = (rbuf == 2) ? 0 : rbuf + 1;
    sbuf = (sbuf == 2) ? 0 : sbuf + 1;
  }
  #undef STAGE_BIG

  // ---- cross-ks reduce via LDS (pad 36 f32/lane), then epilogue ----
  float* red = (float*)SH;
  if (wave >= 8) {
    int rb = (wave - 8) * 2304 + lane * 36;
    #pragma unroll
    for (int i = 0; i < 2; ++i)
      #pragma unroll
      for (int j = 0; j < 4; ++j)
        *(f4v*)(red + rb + (i * 4 + j) * 4) = acc[i][j];
  }
  __syncthreads();
  if (wave < 8) {
    int rb = wave * 2304 + lane * 36;
    #pragma unroll
    for (int i = 0; i < 2; ++i)
      #pragma unroll
      for (int j = 0; j < 4; ++j)
        acc[i][j] += *(const f4v*)(red + rb + (i * 4 + j) * 4);
    #pragma unroll
    for (int i = 0; i < 2; ++i) {
      int rbase = m0 + om * 32 + i * 16 + quad * 4;
      #pragma unroll
      for (int j = 0; j < 4; ++j) {
        int c = n0 + on * 64 + j * 16 + l15;
        #pragma unroll
        for (int rg = 0; rg < 4; ++rg) {
          int r = rbase + rg;
          float v = acc[i][j][rg];
          if (mode == 0) {
            unsigned short* dst = (c < 1024) ? Ob : ((c < 2048) ? Ob2 : Ob3);
            dst[(size_t)r * 1024 + (c & 1023)] = f2bf(v);
          } else {
            v = 0.5f * v * (1.0f + erff(v * 0.70710678118f));
            Ob[(size_t)r * N + c] = f2bf(v);
          }
        }
      }
    }
  }
}

// ---------------------------------------------------------------------------
// K4b v3: bf16 MFMA GEMM, 128x128 tile, 1024 threads = 16 waves, intra-block
// K-split.  Epilogue: O0 = res + mod[gate]*acc (fp32 out).
// ---------------------------------------------------------------------------
__global__ __launch_bounds__(1024) void mfma_gemm_res(
    const unsigned short* __restrict__ A,
    const unsigned short* __restrict__ Bt,
    int M, int N, int K,
    float* __restrict__ O0,
    const float* __restrict__ res, const float* __restrict__ mod,
    int gate_off) {
  __shared__ unsigned short SH[3 * 16384];   // 3 bufs x (A 16KB + B 16KB) = 96 KB
  int tid = threadIdx.x;
  int wave = tid >> 6, lane = tid & 63;
  int quad = lane >> 4, l15 = lane & 15;
  int m0 = blockIdx.y * 128, n0 = blockIdx.x * 128;
  int pos = wave & 7;
  int om = pos >> 1, on = pos & 1;   // 32-row x 64-col output sub-tile
  int ks = wave >> 3;                // K-half (32 of 64) of the outer tile

  f4v acc[2][4] = {};

  int srow = lane >> 3;
  int ksrc = ((lane & 7) ^ (lane >> 3)) << 3;   // source k offset (elems)
  const int nt = K >> 6;

  #define STAGE_RES(T, BUF)                                                    \
    {                                                                          \
      int k0_ = (T) << 6;                                                      \
      unsigned short* dsta = SH + (BUF) * 16384 + wave * 512;                  \
      const unsigned short* ga =                                               \
          A + (size_t)(m0 + 8 * wave + srow) * K + k0_ + ksrc;                 \
      __builtin_amdgcn_global_load_lds(                                        \
          (const __attribute__((address_space(1))) unsigned int*)(const void*)ga, \
          (__attribute__((address_space(3))) unsigned int*)(void*)dsta,        \
          16, 0, 0);                                                           \
      const unsigned short* gb =                                               \
          Bt + (size_t)(n0 + 8 * wave + srow) * K + k0_ + ksrc;                \
      __builtin_amdgcn_global_load_lds(                                        \
          (const __attribute__((address_space(1))) unsigned int*)(const void*)gb, \
          (__attribute__((address_space(3))) unsigned int*)(void*)(dsta + 8192), \
          16, 0, 0);                                                           \
    }

  STAGE_RES(0, 0);
  STAGE_RES(1, 1);
  asm volatile("s_waitcnt vmcnt(2)" ::: "memory");   // tile 0 landed
  __syncthreads();

  int kx = (ks * 32 + quad * 8) ^ ((l15 & 7) << 3);

  int rbuf = 0, sbuf = 2;
  for (int t = 0; t < nt; ++t) {
    if (t + 2 < nt) STAGE_RES(t + 2, sbuf);

    const unsigned short* base = SH + rbuf * 16384;
    s8v af[2], bf[4];
    #pragma unroll
    for (int i = 0; i < 2; ++i)
      af[i] = *(const s8v*)(base + (om * 32 + i * 16 + l15) * 64 + kx);
    #pragma unroll
    for (int j = 0; j < 4; ++j)
      bf[j] = *(const s8v*)(base + 8192 + (on * 64 + j * 16 + l15) * 64 + kx);
    #pragma unroll
    for (int i = 0; i < 2; ++i)
      #pragma unroll
      for (int j = 0; j < 4; ++j)
        acc[i][j] = __builtin_amdgcn_mfma_f32_16x16x32_bf16(
            af[i], bf[j], acc[i][j], 0, 0, 0);

    if (t + 2 < nt) {
      asm volatile("s_waitcnt vmcnt(2)" ::: "memory");   // tile t+1 landed
    } else if (t + 1 < nt) {
      asm volatile("s_waitcnt vmcnt(0)" ::: "memory");
    }
    __syncthreads();
    rbuf = (rbuf == 2) ? 0 : rbuf + 1;
    sbuf = (sbuf == 2) ? 0 : sbuf + 1;
  }
  #undef STAGE_RES

  // ---- cross-ks reduce via LDS (pad 36 f32/lane), then fused epilogue ----
  float* red = (float*)SH;
  if (wave >= 8) {
    int rb = (wave - 8) * 2304 + lane * 36;
    #pragma unroll
    for (int i = 0; i < 2; ++i)
      #pragma unroll
      for (int j = 0; j < 4; ++j)
        *(f4v*)(red + rb + (i * 4 + j) * 4) = acc[i][j];
  }
  __syncthreads();
  if (wave < 8) {
    int rb = wave * 2304 + lane * 36;
    #pragma unroll
    for (int i = 0; i < 2; ++i)
      #pragma unroll
      for (int j = 0; j < 4; ++j)
        acc[i][j] += *(const f4v*)(red + rb + (i * 4 + j) * 4);
    #pragma unroll
    for (int i = 0; i < 2; ++i) {
      int rbase = m0 + om * 32 + i * 16 + quad * 4;
      #pragma unroll
      for (int j = 0; j < 4; ++j) {
        int c = n0 + on * 64 + j * 16 + l15;
        #pragma unroll
        for (int rg = 0; rg < 4; ++rg) {
          int r = rbase + rg;
          int bb2 = r >> 11;
          O0[(size_t)r * N + c] =
              res[(size_t)r * N + c] + mod[bb2 * MODC + gate_off + c] * acc[i][j][rg];
        }
      }
    }
  }
}

// ---------------------------------------------------------------------------
// K5: fused RoPE. y=0: q in-place (scaled by 1/8*log2e). y=1: k -> kpack
// ---------------------------------------------------------------------------
__global__ __launch_bounds__(256) void rope_qk(
    unsigned short* __restrict__ qb, const unsigned short* __restrict__ kb,
    unsigned short* __restrict__ kpack, float qscale) {
  int r = blockIdx.x;            // b*N + n
  int b = r / NN, n = r % NN;
  int t = threadIdx.x;
  int isK = blockIdx.y;
  const unsigned short* src = isK ? kb : qb;
  float scale = isK ? 1.0f : qscale;
  __shared__ float row[CDIM];
  __shared__ float csv[32], snv[32];
  if (t < 32) {
    float invf = powf(10000.0f, -(float)t / 32.0f);
    float sn, cs;
    sincosf((float)n * invf, &sn, &cs);
    csv[t] = cs * scale; snv[t] = sn * scale;
  }
  const unsigned short* qr = src + (size_t)r * CDIM;
  ushort4 xv = ((const ushort4*)qr)[t];
  row[t * 4 + 0] = bf2f(xv.x);
  row[t * 4 + 1] = bf2f(xv.y);
  row[t * 4 + 2] = bf2f(xv.z);
  row[t * 4 + 3] = bf2f(xv.w);
  __syncthreads();
  unsigned short o[4];
  int c0 = t * 4;
  #pragma unroll
  for (int q4 = 0; q4 < 4; ++q4) {
    int c = c0 + q4;
    int h = c >> 6, d = c & 63;
    int i = d & 31;
    float rh = (d < 32) ? -row[h * 64 + 2 * d + 1] : row[h * 64 + 2 * (d - 32)];
    o[q4] = f2bf(row[c] * csv[i] + rh * snv[i]);
  }
  if (!isK) {
    ((ushort4*)(qb + (size_t)r * CDIM))[t] = make_ushort4(o[0], o[1], o[2], o[3]);
  } else {
    int h = c0 >> 6, d0 = c0 & 63;
    int half = d0 >> 5, quad = (d0 >> 3) & 3, j0 = d0 & 7;  // j0 in {0,4}
    int bh = b * HEADS + h;
    int tt = n >> 6, kt = (n >> 4) & 3, l15 = n & 15;
    int lane = quad * 16 + l15;
    size_t off = ((((size_t)bh * 32 + tt) * 8 + kt * 2 + half) * 64 + lane) * 8 + j0;
    unsigned int lo = (unsigned)o[0] | ((unsigned)o[1] << 16);
    unsigned int hi = (unsigned)o[2] | ((unsigned)o[3] << 16);
    *(uint2*)(kpack + off) = make_uint2(lo, hi);
  }
}

// ---------------------------------------------------------------------------
// K5b: V pack  vrow[B*N][1024] -> vpack[bh][t][f=dt*2+half][lane][8]
// ---------------------------------------------------------------------------
__global__ __launch_bounds__(256) void vtrans_pack(
    const unsigned short* __restrict__ vrow, unsigned short* __restrict__ vpack) {
  int t = blockIdx.x;
  int bh = blockIdx.y;
  int b = bh >> 4, h = bh & 15;
  __shared__ unsigned short L[64 * 72];     // L[key][d], pad 72
  int tid = threadIdx.x;
  #pragma unroll
  for (int p = 0; p < 2; ++p) {
    int c = tid + p * 256;
    int key = c >> 3, dc = (c & 7) * 8;
    *(s8v*)(L + key * 72 + dc) =
        *(const s8v*)(vrow + (size_t)(b * NN + t * 64 + key) * CDIM + h * HDIM + dc);
  }
  __syncthreads();
  #pragma unroll
  for (int p = 0; p < 2; ++p) {
    int o = tid + p * 256;
    int f = o >> 6, lane = o & 63;
    int dt = f >> 1, half = f & 1, quad = lane >> 4, l15 = lane & 15;
    int d = dt * 16 + l15;
    unsigned short tmp[8];
    #pragma unroll
    for (int j = 0; j < 8; ++j) {
      int key = (j & 3) * 16 + half * 8 + quad * 2 + (j >> 2);
      tmp[j] = L[key * 72 + d];
    }
    *(s8v*)(vpack + ((((size_t)bh * 32 + t) * 8 + f) * 64 + lane) * 8) = *(s8v*)tmp;
  }
}

// ---------------------------------------------------------------------------
// K6 v6: MFMA flash attention -- pipe-split fragment delivery.
// R10 left the CU-shared DS pipe as the largest term (K+V fragments + P
// round-trip all on DS; L1 idle in the main loop).  R6 proved L1 alone
// sustains a full private V stream at the same rate.  Now: K stays
// LDS-shared (staged via gload_lds, 8 ds_reads/wave-iter); V fragments are
// read DIRECTLY from global to registers (coalesced base+lane*16B, L2-hot),
// removing 8 of 28 DS ops/wave-iter; the two pipes run concurrently.
// + T5 setprio around MFMA clusters (attn-verified +4-7%).
// ---------------------------------------------------------------------------
__global__ __launch_bounds__(512) void fattn_pack(
    const unsigned short* __restrict__ qb,     // [B*N][1024] (scaled)
    const unsigned short* __restrict__ kpack,  // [bh][32][8][64][8]
    const unsigned short* __restrict__ vpack,  // [bh][32][8][64][8]
    unsigned short* __restrict__ ob) {         // [B*N][1024]
  int bid = blockIdx.x;
  int qt = bid >> 5, bh = bid & 31;            // bid%8 == bh%8 -> XCD locality
  int b = bh >> 4, h = bh & 15;
  int tid = threadIdx.x;
  int wave = tid >> 6, lane = tid & 63;
  int quad = lane >> 4, l15 = lane & 15;

  // LDS: 2 K buffers (8KB each) + per-wave P staging (36.9KB) = 53 KB
  __shared__ unsigned short smem[8192 + 8 * 2304];
  unsigned short* Pw = smem + 8192 + wave * 2304;

  int n0 = qt * 256;
  s8v qf[2][2];
  #pragma unroll
  for (int fq = 0; fq < 2; ++fq) {
    int qrow = n0 + wave * 32 + fq * 16 + l15;
    const unsigned short* qp = qb + (size_t)(b * NN + qrow) * CDIM + h * HDIM;
    qf[fq][0] = *(const s8v*)(qp + quad * 8);
    qf[fq][1] = *(const s8v*)(qp + 32 + quad * 8);
  }

  f4v acc[2][4] = {};
  float m_i[2][4], l_i[2][4];
  #pragma unroll
  for (int fq = 0; fq < 2; ++fq)
    #pragma unroll
    for (int r = 0; r < 4; ++r) { m_i[fq][r] = -1e30f; l_i[fq][r] = 0.f; }

  // K staging source: fragment #wave of the K tile (wave-uniform base)
  const unsigned short* ksrc = kpack + (size_t)bh * 131072 + wave * 512 + lane * 8;
  // V register source: full tile per wave, coalesced base + lane*16B
  const unsigned short* vsrc = vpack + (size_t)bh * 131072 + lane * 8;

  #define STAGE_ATT(T, BUF)                                                    \
    {                                                                          \
      __builtin_amdgcn_global_load_lds(                                        \
          (const __attribute__((address_space(1))) unsigned int*)(const void*)(ksrc + (size_t)(T) * 4096), \
          (__attribute__((address_space(3))) unsigned int*)(void*)(smem + (BUF) * 4096 + wave * 512), \
          16, 0, 0);                                                           \
    }

  STAGE_ATT(0, 0);
  asm volatile("s_waitcnt vmcnt(0)" ::: "memory");
  __syncthreads();

  int buf = 0;
  for (int t = 0; t < NN / 64; ++t) {
    if (t + 1 < NN / 64) STAGE_ATT(t + 1, buf ^ 1);

    // ---- V fragments: global -> registers (L1/L2 pipe, latency hidden
    //      under QK^T + softmax) ----
    s8v vf[8];
    {
      const unsigned short* vt_ = vsrc + (size_t)t * 4096;
      #pragma unroll
      for (int f = 0; f < 8; ++f) vf[f] = *(const s8v*)(vt_ + f * 512);
    }

    // ---- K fragments from shared LDS; S = Q K^T ----
    f4v s4[2][4];
    {
      const unsigned short* kb_ = smem + buf * 4096 + lane * 8;
      s8v kf[8];
      #pragma unroll
      for (int f = 0; f < 8; ++f) kf[f] = *(const s8v*)(kb_ + f * 512);
      __builtin_amdgcn_s_setprio(1);
      #pragma unroll
      for (int fq = 0; fq < 2; ++fq)
        #pragma unroll
        for (int kt = 0; kt < 4; ++kt) {
          f4v z = {};
          z = __builtin_amdgcn_mfma_f32_16x16x32_bf16(qf[fq][0], kf[kt * 2], z, 0, 0, 0);
          z = __builtin_amdgcn_mfma_f32_16x16x32_bf16(qf[fq][1], kf[kt * 2 + 1], z, 0, 0, 0);
          s4[fq][kt] = z;
        }
      __builtin_amdgcn_s_setprio(0);
    }

    // ---- online softmax: DPP max reduce + defer-max (T13, THR=8 exp2) ----
    #pragma unroll
    for (int fq = 0; fq < 2; ++fq)
      #pragma unroll
      for (int r = 0; r < 4; ++r) {
        float mv = fmaxf(fmaxf(s4[fq][0][r], s4[fq][1][r]),
                         fmaxf(s4[fq][2][r], s4[fq][3][r]));
        mv = max16(mv);
        if (!__all(mv - m_i[fq][r] <= 8.0f)) {
          float mnew = fmaxf(m_i[fq][r], mv);
          float alpha = __builtin_amdgcn_exp2f(m_i[fq][r] - mnew);
          m_i[fq][r] = mnew;
          l_i[fq][r] *= alpha;
          acc[fq][0][r] *= alpha; acc[fq][1][r] *= alpha;
          acc[fq][2][r] *= alpha; acc[fq][3][r] *= alpha;
        }
        float ls = 0.f;
        #pragma unroll
        for (int kt = 0; kt < 4; ++kt) {
          float p = __builtin_amdgcn_exp2f(s4[fq][kt][r] - m_i[fq][r]);
          s4[fq][kt][r] = p;
          ls += p;
        }
        l_i[fq][r] += ls;
      }

    // ---- P -> wave-private LDS, permuted keys (b64 writes) ----
    #pragma unroll
    for (int fq = 0; fq < 2; ++fq)
      #pragma unroll
      for (int r = 0; r < 4; ++r) {
        unsigned int lo = (__float_as_uint(s4[fq][0][r]) >> 16) |
                          (__float_as_uint(s4[fq][1][r]) & 0xffff0000u);
        unsigned int hi = (__float_as_uint(s4[fq][2][r]) >> 16) |
                          (__float_as_uint(s4[fq][3][r]) & 0xffff0000u);
        *(uint2*)(Pw + (fq * 16 + quad * 4 + r) * 72 + l15 * 4) = make_uint2(lo, hi);
      }

    // ---- acc += P V (V already in registers) ----
    #pragma unroll
    for (int fq = 0; fq < 2; ++fq) {
      s8v pf0 = *(const s8v*)(Pw + (fq * 16 + l15) * 72 + quad * 8);
      s8v pf1 = *(const s8v*)(Pw + (fq * 16 + l15) * 72 + 32 + quad * 8);
      __builtin_amdgcn_s_setprio(1);
      #pragma unroll
      for (int dt = 0; dt < 4; ++dt) {
        acc[fq][dt] = __builtin_amdgcn_mfma_f32_16x16x32_bf16(pf0, vf[dt * 2], acc[fq][dt], 0, 0, 0);
        acc[fq][dt] = __builtin_amdgcn_mfma_f32_16x16x32_bf16(pf1, vf[dt * 2 + 1], acc[fq][dt], 0, 0, 0);
      }
      __builtin_amdgcn_s_setprio(0);
    }

    if (t + 1 < NN / 64) {
      asm volatile("s_waitcnt vmcnt(0)" ::: "memory");   // next K tile landed
      __syncthreads();
      buf ^= 1;
    }
  }
  #undef STAGE_ATT

  // ---- epilogue ----
  #pragma unroll
  for (int fq = 0; fq < 2; ++fq)
    #pragma unroll
    for (int r = 0; r < 4; ++r) {
      float l = l_i[fq][r];
      #pragma unroll
      for (int msk = 1; msk < 16; msk <<= 1)
        l += __shfl_xor(l, msk, 64);
      float inv = 1.0f / l;
      size_t row = (size_t)(b * NN + n0 + wave * 32 + fq * 16 + quad * 4 + r);
      unsigned short* op = ob + row * CDIM + h * HDIM;
      #pragma unroll
      for (int dt = 0; dt < 4; ++dt)
        op[dt * 16 + l15] = f2bf(acc[fq][dt][r] * inv);
    }
}

// ---------------------------------------------------------------------------
extern "C" void kernel_launch(void* const* d_in, const int* in_sizes, int n_in,
                              void* d_out, int out_size, void* d_ws, size_t ws_size,
                              hipStream_t stream) {
  const float* x    = (const float*)d_in[0];
  const float* temb = (const float*)d_in[1];
  const float* n1g  = (const float*)d_in[2];
  const float* n1b  = (const float*)d_in[3];
  const float* Wq   = (const float*)d_in[4];
  const float* Wk   = (const float*)d_in[5];
  const float* Wv   = (const float*)d_in[6];
  const float* Wo   = (const float*)d_in[7];
  const float* n2g  = (const float*)d_in[8];
  const float* n2b  = (const float*)d_in[9];
  const float* W1   = (const float*)d_in[10];
  const float* W2   = (const float*)d_in[11];
  const float* adaW = (const float*)d_in[12];
  const float* adab = (const float*)d_in[13];
  float* out = (float*)d_out;

  const size_t TOK = (size_t)BB * NN * CDIM;   // 4,194,304
  float* wsf = (float*)d_ws;
  float* mod     = wsf;                                    // 16384 f32
  float* modpart = wsf + 16384;                            // 16*2*6144 f32
  unsigned short* tokb  = (unsigned short*)(wsf + 16384 + MSPLIT * BB * MODC);
  unsigned short* qb    = tokb + TOK;
  unsigned short* kb    = qb + TOK;
  unsigned short* kpack = kb + TOK;
  unsigned short* vpack = kpack + TOK;
  unsigned short* Wqkvt = vpack + TOK;                     // 3M u16
  unsigned short* Wot   = Wqkvt + 3 * CDIM * CDIM;         // 1M
  unsigned short* W1t   = Wot + CDIM * CDIM;               // 4M
  unsigned short* W2t   = W1t + CDIM * MLPD;               // 4M
  unsigned short* h1b   = W2t + MLPD * CDIM;               // 16.7M u16
  unsigned short* vrow  = h1b;          // staging alias (dead before W1 GEMM)
  float* x1 = (float*)qb;               // fp32 alias over qb+kb (dead after fattn)

  const int M = BB * NN;   // 4096

  mod_part<<<dim3(MODC / 256, BB, MSPLIT), 256, 0, stream>>>(temb, adaW, modpart);
  mod_reduce<<<dim3(BB * MODC / 256), 256, 0, stream>>>(modpart, adab, mod);
  ln_mod_bf16<<<dim3(M), 256, 0, stream>>>(x, n1g, n1b, mod, 0, 1024, tokb);

  wcast_all<<<dim3(12288), 256, 0, stream>>>(
      Wq, Wk, Wv, Wo, W1, W2, Wqkvt, Wot, W1t, W2t);

  // fused QKV -> q,k,v row-major bf16
  mfma_gemm_big<<<dim3(24, 32), 1024, 0, stream>>>(
      tokb, Wqkvt, M, 3 * CDIM, CDIM, qb, kb, vrow, 0);

  rope_qk<<<dim3(M, 2), 256, 0, stream>>>(qb, kb, kpack, 0.125f * LOG2E);

  vtrans_pack<<<dim3(NN / 64, BB * HEADS), 256, 0, stream>>>(vrow, vpack);

  fattn_pack<<<dim3((NN / 256) * BB * HEADS), 512, 0, stream>>>(
      qb, kpack, vpack, tokb);

  // x1 = x + gate_msa * (attn @ Wo)
  mfma_gemm_res<<<dim3(CDIM / 128, M / 128), 1024, 0, stream>>>(
      tokb, Wot, M, CDIM, CDIM, x1, x, mod, 2048);

  ln_mod_bf16<<<dim3(M), 256, 0, stream>>>(x1, n2g, n2b, mod, 3072, 4096, tokb);

  // h1 = gelu(xn2 @ W1)
  mfma_gemm_big<<<dim3(MLPD / 128, M / 128), 1024, 0, stream>>>(
      tokb, W1t, M, MLPD, CDIM, h1b, nullptr, nullptr, 1);

  // out = x1 + gate_mlp * (h1 @ W2)
  mfma_gemm_res<<<dim3(CDIM / 128, M / 128), 1024, 0, stream>>>(
      h1b, W2t, M, CDIM, MLPD, out, x1, mod, 5120);
}

// Round 13
// 422.832 us; speedup vs baseline: 1.0155x; 1.0155x over previous
//
#include <hip/hip_runtime.h>
#include <math.h>

#define BB    2
#define NN    2048
#define CDIM  1024
#define HEADS 16
#define HDIM  64
#define MLPD  4096
#define MODC  6144
#define EPSV  1e-5f
#define LOG2E 1.4426950408889634f
#define MSPLIT 16

typedef __attribute__((ext_vector_type(8))) short s8v;     // 8 bf16 (4 VGPRs)
typedef __attribute__((ext_vector_type(4))) float f4v;     // MFMA C/D

__device__ inline unsigned short f2bf(float f) {
  union { float f; unsigned u; } v; v.f = f;
  unsigned r = v.u + 0x7FFFu + ((v.u >> 16) & 1u);   // RNE
  return (unsigned short)(r >> 16);
}
__device__ inline float bf2f(unsigned short h) {
  union { unsigned u; float f; } v; v.u = ((unsigned)h) << 16;
  return v.f;
}

// DPP 16-lane max reduce: VALU-only (no ds_swizzle -> keeps the DS pipe free).
template<int CTRL>
__device__ __forceinline__ float dpp_max_step(float v) {
  int iv = __float_as_int(v);
  int sh = __builtin_amdgcn_update_dpp(iv, iv, CTRL, 0xF, 0xF, false);
  return fmaxf(v, __int_as_float(sh));
}
__device__ __forceinline__ float max16(float v) {
  v = dpp_max_step<0xB1>(v);    // quad_perm [1,0,3,2]  (xor 1)
  v = dpp_max_step<0x4E>(v);    // quad_perm [2,3,0,1]  (xor 2)
  v = dpp_max_step<0x124>(v);   // row_ror:4
  v = dpp_max_step<0x128>(v);   // row_ror:8
  return v;
}

// ---------------------------------------------------------------------------
// K1a: split-K partials for mod = silu(t_emb) @ ada_W
// ---------------------------------------------------------------------------
__global__ __launch_bounds__(256) void mod_part(
    const float* __restrict__ t_emb, const float* __restrict__ ada_W,
    float* __restrict__ part) {
  int j = blockIdx.x * 256 + threadIdx.x;
  int b = blockIdx.y, ks = blockIdx.z;
  __shared__ float st[64];
  if (threadIdx.x < 64) {
    float v = t_emb[b * CDIM + ks * 64 + threadIdx.x];
    st[threadIdx.x] = v / (1.0f + expf(-v));
  }
  __syncthreads();
  float acc = 0.f;
  const float* wp = ada_W + (size_t)(ks * 64) * MODC + j;
  #pragma unroll 8
  for (int i = 0; i < 64; ++i) acc += st[i] * wp[(size_t)i * MODC];
  part[((size_t)ks * BB + b) * MODC + j] = acc;
}

// K1b: reduce partials + bias
__global__ __launch_bounds__(256) void mod_reduce(
    const float* __restrict__ part, const float* __restrict__ ada_b,
    float* __restrict__ mod) {
  int idx = blockIdx.x * 256 + threadIdx.x;   // 0 .. B*MODC-1
  int b = idx / MODC, j = idx % MODC;
  float a = ada_b[j];
  #pragma unroll
  for (int s = 0; s < MSPLIT; ++s) a += part[((size_t)s * BB + b) * MODC + j];
  mod[(size_t)b * MODC + j] = a;
}

// ---------------------------------------------------------------------------
// K2: LN + adaLN modulation, bf16 output
// ---------------------------------------------------------------------------
__device__ inline float wave_sum64(float v) {
  for (int o = 32; o > 0; o >>= 1) v += __shfl_down(v, o, 64);
  return v;
}

__global__ __launch_bounds__(256) void ln_mod_bf16(
    const float* __restrict__ x, const float* __restrict__ g,
    const float* __restrict__ bta, const float* __restrict__ mod,
    int shift_off, int scale_off, unsigned short* __restrict__ out) {
  int r = blockIdx.x;
  int b = r / NN;
  int t = threadIdx.x;
  const float* xr = x + (size_t)r * CDIM;
  float4 xv = ((const float4*)xr)[t];
  float s  = xv.x + xv.y + xv.z + xv.w;
  float s2 = xv.x*xv.x + xv.y*xv.y + xv.z*xv.z + xv.w*xv.w;
  __shared__ float ws1[4], ws2[4];
  float sw = wave_sum64(s), s2w = wave_sum64(s2);
  int lane = t & 63, wid = t >> 6;
  if (lane == 0) { ws1[wid] = sw; ws2[wid] = s2w; }
  __syncthreads();
  float mu  = (ws1[0] + ws1[1] + ws1[2] + ws1[3]) * (1.0f / CDIM);
  float var = (ws2[0] + ws2[1] + ws2[2] + ws2[3]) * (1.0f / CDIM) - mu * mu;
  float rstd = rsqrtf(var + EPSV);
  const float* mods = mod + (size_t)b * MODC;
  float4 gv = ((const float4*)g)[t];
  float4 bv = ((const float4*)bta)[t];
  float4 sc = ((const float4*)(mods + scale_off))[t];
  float4 sh = ((const float4*)(mods + shift_off))[t];
  ushort4 ov;
  ov.x = f2bf(((xv.x - mu) * rstd * gv.x + bv.x) * (1.0f + sc.x) + sh.x);
  ov.y = f2bf(((xv.y - mu) * rstd * gv.y + bv.y) * (1.0f + sc.y) + sh.y);
  ov.z = f2bf(((xv.z - mu) * rstd * gv.z + bv.z) * (1.0f + sc.z) + sh.z);
  ov.w = f2bf(((xv.w - mu) * rstd * gv.w + bv.w) * (1.0f + sc.w) + sh.w);
  ((ushort4*)(out + (size_t)r * CDIM))[t] = ov;
}

// ---------------------------------------------------------------------------
// K3: ALL weight transpose-casts in one launch.  W[K][N] f32 -> Wt[N][K] bf16
// ---------------------------------------------------------------------------
__global__ __launch_bounds__(256) void wcast_all(
    const float* __restrict__ Wq, const float* __restrict__ Wk,
    const float* __restrict__ Wv, const float* __restrict__ Wo,
    const float* __restrict__ W1, const float* __restrict__ W2,
    unsigned short* __restrict__ Wqkvt, unsigned short* __restrict__ Wot,
    unsigned short* __restrict__ W1t, unsigned short* __restrict__ W2t) {
  int bid = blockIdx.x;
  const float* W; unsigned short* Wt; int K, N, t;
  if (bid < 4096) {
    int m = bid >> 10;
    t = bid & 1023;
    K = CDIM; N = CDIM;
    W  = (m == 0) ? Wq : (m == 1) ? Wk : (m == 2) ? Wv : Wo;
    Wt = (m == 3) ? Wot : (Wqkvt + (size_t)m * CDIM * CDIM);
  } else if (bid < 8192) {
    t = bid - 4096; K = CDIM; N = MLPD; W = W1; Wt = W1t;
  } else {
    t = bid - 8192; K = MLPD; N = CDIM; W = W2; Wt = W2t;
  }
  int ntiles = N >> 5;
  int n0 = (t % ntiles) * 32, k0 = (t / ntiles) * 32;
  __shared__ float tile[32][33];
  int tx = threadIdx.x & 31, ty = threadIdx.x >> 5;
  #pragma unroll
  for (int p = 0; p < 4; ++p)
    tile[ty + p * 8][tx] = W[(size_t)(k0 + ty + p * 8) * N + n0 + tx];
  __syncthreads();
  #pragma unroll
  for (int p = 0; p < 4; ++p)
    Wt[(size_t)(n0 + ty + p * 8) * K + k0 + tx] = f2bf(tile[tx][ty + p * 8]);
}

// ---------------------------------------------------------------------------
// K4 v3: bf16 MFMA GEMM, 128x128 tile, 1024 threads = 16 waves, intra-block
// K-split.  Epilogues: mode 0 = QKV 3-way split; mode 1 = exact GELU bf16.
// ---------------------------------------------------------------------------
__global__ __launch_bounds__(1024) void mfma_gemm_big(
    const unsigned short* __restrict__ A,
    const unsigned short* __restrict__ Bt,
    int M, int N, int K,
    unsigned short* __restrict__ Ob, unsigned short* __restrict__ Ob2,
    unsigned short* __restrict__ Ob3, int mode) {
  __shared__ unsigned short SH[3 * 16384];   // 3 bufs x (A 16KB + B 16KB) = 96 KB
  int tid = threadIdx.x;
  int wave = tid >> 6, lane = tid & 63;
  int quad = lane >> 4, l15 = lane & 15;
  int m0 = blockIdx.y * 128, n0 = blockIdx.x * 128;
  int pos = wave & 7;
  int om = pos >> 1, on = pos & 1;   // 32-row x 64-col output sub-tile
  int ks = wave >> 3;                // K-half (32 of 64) of the outer tile

  f4v acc[2][4] = {};

  int srow = lane >> 3;
  int ksrc = ((lane & 7) ^ (lane >> 3)) << 3;   // source k offset (elems)
  const int nt = K >> 6;

  #define STAGE_BIG(T, BUF)                                                    \
    {                                                                          \
      int k0_ = (T) << 6;                                                      \
      unsigned short* dsta = SH + (BUF) * 16384 + wave * 512;                  \
      const unsigned short* ga =                                               \
          A + (size_t)(m0 + 8 * wave + srow) * K + k0_ + ksrc;                 \
      __builtin_amdgcn_global_load_lds(                                        \
          (const __attribute__((address_space(1))) unsigned int*)(const void*)ga, \
          (__attribute__((address_space(3))) unsigned int*)(void*)dsta,        \
          16, 0, 0);                                                           \
      const unsigned short* gb =                                               \
          Bt + (size_t)(n0 + 8 * wave + srow) * K + k0_ + ksrc;                \
      __builtin_amdgcn_global_load_lds(                                        \
          (const __attribute__((address_space(1))) unsigned int*)(const void*)gb, \
          (__attribute__((address_space(3))) unsigned int*)(void*)(dsta + 8192), \
          16, 0, 0);                                                           \
    }

  STAGE_BIG(0, 0);
  STAGE_BIG(1, 1);
  asm volatile("s_waitcnt vmcnt(2)" ::: "memory");   // tile 0 landed
  __syncthreads();

  int kx = (ks * 32 + quad * 8) ^ ((l15 & 7) << 3);

  int rbuf = 0, sbuf = 2;
  for (int t = 0; t < nt; ++t) {
    if (t + 2 < nt) STAGE_BIG(t + 2, sbuf);

    const unsigned short* base = SH + rbuf * 16384;
    s8v af[2], bf[4];
    #pragma unroll
    for (int i = 0; i < 2; ++i)
      af[i] = *(const s8v*)(base + (om * 32 + i * 16 + l15) * 64 + kx);
    #pragma unroll
    for (int j = 0; j < 4; ++j)
      bf[j] = *(const s8v*)(base + 8192 + (on * 64 + j * 16 + l15) * 64 + kx);
    #pragma unroll
    for (int i = 0; i < 2; ++i)
      #pragma unroll
      for (int j = 0; j < 4; ++j)
        acc[i][j] = __builtin_amdgcn_mfma_f32_16x16x32_bf16(
            af[i], bf[j], acc[i][j], 0, 0, 0);

    if (t + 2 < nt) {
      asm volatile("s_waitcnt vmcnt(2)" ::: "memory");   // tile t+1 landed
    } else if (t + 1 < nt) {
      asm volatile("s_waitcnt vmcnt(0)" ::: "memory");
    }
    __syncthreads();
    rbuf = (rbuf == 2) ? 0 : rbuf + 1;
    sbuf = (sbuf == 2) ? 0 : sbuf + 1;
  }
  #undef STAGE_BIG

  // ---- cross-ks reduce via LDS (pad 36 f32/lane), then epilogue ----
  float* red = (float*)SH;
  if (wave >= 8) {
    int rb = (wave - 8) * 2304 + lane * 36;
    #pragma unroll
    for (int i = 0; i < 2; ++i)
      #pragma unroll
      for (int j = 0; j < 4; ++j)
        *(f4v*)(red + rb + (i * 4 + j) * 4) = acc[i][j];
  }
  __syncthreads();
  if (wave < 8) {
    int rb = wave * 2304 + lane * 36;
    #pragma unroll
    for (int i = 0; i < 2; ++i)
      #pragma unroll
      for (int j = 0; j < 4; ++j)
        acc[i][j] += *(const f4v*)(red + rb + (i * 4 + j) * 4);
    #pragma unroll
    for (int i = 0; i < 2; ++i) {
      int rbase = m0 + om * 32 + i * 16 + quad * 4;
      #pragma unroll
      for (int j = 0; j < 4; ++j) {
        int c = n0 + on * 64 + j * 16 + l15;
        #pragma unroll
        for (int rg = 0; rg < 4; ++rg) {
          int r = rbase + rg;
          float v = acc[i][j][rg];
          if (mode == 0) {
            unsigned short* dst = (c < 1024) ? Ob : ((c < 2048) ? Ob2 : Ob3);
            dst[(size_t)r * 1024 + (c & 1023)] = f2bf(v);
          } else {
            v = 0.5f * v * (1.0f + erff(v * 0.70710678118f));
            Ob[(size_t)r * N + c] = f2bf(v);
          }
        }
      }
    }
  }
}

// ---------------------------------------------------------------------------
// K4b v3: bf16 MFMA GEMM, 128x128 tile, 1024 threads = 16 waves, intra-block
// K-split.  Epilogue: O0 = res + mod[gate]*acc (fp32 out).
// ---------------------------------------------------------------------------
__global__ __launch_bounds__(1024) void mfma_gemm_res(
    const unsigned short* __restrict__ A,
    const unsigned short* __restrict__ Bt,
    int M, int N, int K,
    float* __restrict__ O0,
    const float* __restrict__ res, const float* __restrict__ mod,
    int gate_off) {
  __shared__ unsigned short SH[3 * 16384];   // 3 bufs x (A 16KB + B 16KB) = 96 KB
  int tid = threadIdx.x;
  int wave = tid >> 6, lane = tid & 63;
  int quad = lane >> 4, l15 = lane & 15;
  int m0 = blockIdx.y * 128, n0 = blockIdx.x * 128;
  int pos = wave & 7;
  int om = pos >> 1, on = pos & 1;   // 32-row x 64-col output sub-tile
  int ks = wave >> 3;                // K-half (32 of 64) of the outer tile

  f4v acc[2][4] = {};

  int srow = lane >> 3;
  int ksrc = ((lane & 7) ^ (lane >> 3)) << 3;   // source k offset (elems)
  const int nt = K >> 6;

  #define STAGE_RES(T, BUF)                                                    \
    {                                                                          \
      int k0_ = (T) << 6;                                                      \
      unsigned short* dsta = SH + (BUF) * 16384 + wave * 512;                  \
      const unsigned short* ga =                                               \
          A + (size_t)(m0 + 8 * wave + srow) * K + k0_ + ksrc;                 \
      __builtin_amdgcn_global_load_lds(                                        \
          (const __attribute__((address_space(1))) unsigned int*)(const void*)ga, \
          (__attribute__((address_space(3))) unsigned int*)(void*)dsta,        \
          16, 0, 0);                                                           \
      const unsigned short* gb =                                               \
          Bt + (size_t)(n0 + 8 * wave + srow) * K + k0_ + ksrc;                \
      __builtin_amdgcn_global_load_lds(                                        \
          (const __attribute__((address_space(1))) unsigned int*)(const void*)gb, \
          (__attribute__((address_space(3))) unsigned int*)(void*)(dsta + 8192), \
          16, 0, 0);                                                           \
    }

  STAGE_RES(0, 0);
  STAGE_RES(1, 1);
  asm volatile("s_waitcnt vmcnt(2)" ::: "memory");   // tile 0 landed
  __syncthreads();

  int kx = (ks * 32 + quad * 8) ^ ((l15 & 7) << 3);

  int rbuf = 0, sbuf = 2;
  for (int t = 0; t < nt; ++t) {
    if (t + 2 < nt) STAGE_RES(t + 2, sbuf);

    const unsigned short* base = SH + rbuf * 16384;
    s8v af[2], bf[4];
    #pragma unroll
    for (int i = 0; i < 2; ++i)
      af[i] = *(const s8v*)(base + (om * 32 + i * 16 + l15) * 64 + kx);
    #pragma unroll
    for (int j = 0; j < 4; ++j)
      bf[j] = *(const s8v*)(base + 8192 + (on * 64 + j * 16 + l15) * 64 + kx);
    #pragma unroll
    for (int i = 0; i < 2; ++i)
      #pragma unroll
      for (int j = 0; j < 4; ++j)
        acc[i][j] = __builtin_amdgcn_mfma_f32_16x16x32_bf16(
            af[i], bf[j], acc[i][j], 0, 0, 0);

    if (t + 2 < nt) {
      asm volatile("s_waitcnt vmcnt(2)" ::: "memory");   // tile t+1 landed
    } else if (t + 1 < nt) {
      asm volatile("s_waitcnt vmcnt(0)" ::: "memory");
    }
    __syncthreads();
    rbuf = (rbuf == 2) ? 0 : rbuf + 1;
    sbuf = (sbuf == 2) ? 0 : sbuf + 1;
  }
  #undef STAGE_RES

  // ---- cross-ks reduce via LDS (pad 36 f32/lane), then fused epilogue ----
  float* red = (float*)SH;
  if (wave >= 8) {
    int rb = (wave - 8) * 2304 + lane * 36;
    #pragma unroll
    for (int i = 0; i < 2; ++i)
      #pragma unroll
      for (int j = 0; j < 4; ++j)
        *(f4v*)(red + rb + (i * 4 + j) * 4) = acc[i][j];
  }
  __syncthreads();
  if (wave < 8) {
    int rb = wave * 2304 + lane * 36;
    #pragma unroll
    for (int i = 0; i < 2; ++i)
      #pragma unroll
      for (int j = 0; j < 4; ++j)
        acc[i][j] += *(const f4v*)(red + rb + (i * 4 + j) * 4);
    #pragma unroll
    for (int i = 0; i < 2; ++i) {
      int rbase = m0 + om * 32 + i * 16 + quad * 4;
      #pragma unroll
      for (int j = 0; j < 4; ++j) {
        int c = n0 + on * 64 + j * 16 + l15;
        #pragma unroll
        for (int rg = 0; rg < 4; ++rg) {
          int r = rbase + rg;
          int bb2 = r >> 11;
          O0[(size_t)r * N + c] =
              res[(size_t)r * N + c] + mod[bb2 * MODC + gate_off + c] * acc[i][j][rg];
        }
      }
    }
  }
}

// ---------------------------------------------------------------------------
// K5: fused RoPE. y=0: q in-place (scaled by 1/8*log2e). y=1: k -> kpack
// ---------------------------------------------------------------------------
__global__ __launch_bounds__(256) void rope_qk(
    unsigned short* __restrict__ qb, const unsigned short* __restrict__ kb,
    unsigned short* __restrict__ kpack, float qscale) {
  int r = blockIdx.x;            // b*N + n
  int b = r / NN, n = r % NN;
  int t = threadIdx.x;
  int isK = blockIdx.y;
  const unsigned short* src = isK ? kb : qb;
  float scale = isK ? 1.0f : qscale;
  __shared__ float row[CDIM];
  __shared__ float csv[32], snv[32];
  if (t < 32) {
    float invf = powf(10000.0f, -(float)t / 32.0f);
    float sn, cs;
    sincosf((float)n * invf, &sn, &cs);
    csv[t] = cs * scale; snv[t] = sn * scale;
  }
  const unsigned short* qr = src + (size_t)r * CDIM;
  ushort4 xv = ((const ushort4*)qr)[t];
  row[t * 4 + 0] = bf2f(xv.x);
  row[t * 4 + 1] = bf2f(xv.y);
  row[t * 4 + 2] = bf2f(xv.z);
  row[t * 4 + 3] = bf2f(xv.w);
  __syncthreads();
  unsigned short o[4];
  int c0 = t * 4;
  #pragma unroll
  for (int q4 = 0; q4 < 4; ++q4) {
    int c = c0 + q4;
    int h = c >> 6, d = c & 63;
    int i = d & 31;
    float rh = (d < 32) ? -row[h * 64 + 2 * d + 1] : row[h * 64 + 2 * (d - 32)];
    o[q4] = f2bf(row[c] * csv[i] + rh * snv[i]);
  }
  if (!isK) {
    ((ushort4*)(qb + (size_t)r * CDIM))[t] = make_ushort4(o[0], o[1], o[2], o[3]);
  } else {
    int h = c0 >> 6, d0 = c0 & 63;
    int half = d0 >> 5, quad = (d0 >> 3) & 3, j0 = d0 & 7;  // j0 in {0,4}
    int bh = b * HEADS + h;
    int tt = n >> 6, kt = (n >> 4) & 3, l15 = n & 15;
    int lane = quad * 16 + l15;
    size_t off = ((((size_t)bh * 32 + tt) * 8 + kt * 2 + half) * 64 + lane) * 8 + j0;
    unsigned int lo = (unsigned)o[0] | ((unsigned)o[1] << 16);
    unsigned int hi = (unsigned)o[2] | ((unsigned)o[3] << 16);
    *(uint2*)(kpack + off) = make_uint2(lo, hi);
  }
}

// ---------------------------------------------------------------------------
// K5b: V pack  vrow[B*N][1024] -> vpack[bh][t][f=dt*2+half][lane][8]
// ---------------------------------------------------------------------------
__global__ __launch_bounds__(256) void vtrans_pack(
    const unsigned short* __restrict__ vrow, unsigned short* __restrict__ vpack) {
  int t = blockIdx.x;
  int bh = blockIdx.y;
  int b = bh >> 4, h = bh & 15;
  __shared__ unsigned short L[64 * 72];     // L[key][d], pad 72
  int tid = threadIdx.x;
  #pragma unroll
  for (int p = 0; p < 2; ++p) {
    int c = tid + p * 256;
    int key = c >> 3, dc = (c & 7) * 8;
    *(s8v*)(L + key * 72 + dc) =
        *(const s8v*)(vrow + (size_t)(b * NN + t * 64 + key) * CDIM + h * HDIM + dc);
  }
  __syncthreads();
  #pragma unroll
  for (int p = 0; p < 2; ++p) {
    int o = tid + p * 256;
    int f = o >> 6, lane = o & 63;
    int dt = f >> 1, half = f & 1, quad = lane >> 4, l15 = lane & 15;
    int d = dt * 16 + l15;
    unsigned short tmp[8];
    #pragma unroll
    for (int j = 0; j < 8; ++j) {
      int key = (j & 3) * 16 + half * 8 + quad * 2 + (j >> 2);
      tmp[j] = L[key * 72 + d];
    }
    *(s8v*)(vpack + ((((size_t)bh * 32 + t) * 8 + f) * 64 + lane) * 8) = *(s8v*)tmp;
  }
}

// ---------------------------------------------------------------------------
// K6 v7: R10-exact structure (K+V LDS-shared, DPP max, defer-max, NO
// setprio -- R11 A/B showed the setprio+pipe-split bundle regressed 77->82;
// lockstep barrier-synced waves are T5's null regime) + staging depth 2
// with counted vmcnt(2) (the proven mfma_gemm_res pattern): stage tile t+2
// into buf (t+2)%3, wait "tile t+1 landed" -- never drain to 0 mid-loop.
// Race-safe: buf (t+2)%3 last ds_read at iter t-1, complete before that
// iteration's barrier.  LDS 3x16KB KV + 36.9KB P = 84.9 KB (1 block/CU,
// grid = 256 = CU count anyway).
// ---------------------------------------------------------------------------
__global__ __launch_bounds__(512) void fattn_pack(
    const unsigned short* __restrict__ qb,     // [B*N][1024] (scaled)
    const unsigned short* __restrict__ kpack,  // [bh][32][8][64][8]
    const unsigned short* __restrict__ vpack,  // [bh][32][8][64][8]
    unsigned short* __restrict__ ob) {         // [B*N][1024]
  int bid = blockIdx.x;
  int qt = bid >> 5, bh = bid & 31;            // bid%8 == bh%8 -> XCD locality
  int b = bh >> 4, h = bh & 15;
  int tid = threadIdx.x;
  int wave = tid >> 6, lane = tid & 63;
  int quad = lane >> 4, l15 = lane & 15;

  // LDS: 3 KV buffers (16KB each: K 8KB | V 8KB) + per-wave P staging
  __shared__ unsigned short smem[3 * 8192 + 8 * 2304];
  unsigned short* Pw = smem + 3 * 8192 + wave * 2304;

  int n0 = qt * 256;
  s8v qf[2][2];
  #pragma unroll
  for (int fq = 0; fq < 2; ++fq) {
    int qrow = n0 + wave * 32 + fq * 16 + l15;
    const unsigned short* qp = qb + (size_t)(b * NN + qrow) * CDIM + h * HDIM;
    qf[fq][0] = *(const s8v*)(qp + quad * 8);
    qf[fq][1] = *(const s8v*)(qp + 32 + quad * 8);
  }

  f4v acc[2][4] = {};
  float m_i[2][4], l_i[2][4];
  #pragma unroll
  for (int fq = 0; fq < 2; ++fq)
    #pragma unroll
    for (int r = 0; r < 4; ++r) { m_i[fq][r] = -1e30f; l_i[fq][r] = 0.f; }

  // per-wave global source: fragment #wave of the K / V tile
  const unsigned short* ksrc = kpack + (size_t)bh * 131072 + wave * 512 + lane * 8;
  const unsigned short* vsrc = vpack + (size_t)bh * 131072 + wave * 512 + lane * 8;

  // stage tile T into buffer BUF (u16 offsets: buf*8192; V at +4096)
  #define STAGE_ATT(T, BUF)                                                    \
    {                                                                          \
      __builtin_amdgcn_global_load_lds(                                        \
          (const __attribute__((address_space(1))) unsigned int*)(const void*)(ksrc + (size_t)(T) * 4096), \
          (__attribute__((address_space(3))) unsigned int*)(void*)(smem + (BUF) * 8192 + wave * 512), \
          16, 0, 0);                                                           \
      __builtin_amdgcn_global_load_lds(                                        \
          (const __attribute__((address_space(1))) unsigned int*)(const void*)(vsrc + (size_t)(T) * 4096), \
          (__attribute__((address_space(3))) unsigned int*)(void*)(smem + (BUF) * 8192 + 4096 + wave * 512), \
          16, 0, 0);                                                           \
    }

  const int NT = NN / 64;
  STAGE_ATT(0, 0);
  STAGE_ATT(1, 1);
  asm volatile("s_waitcnt vmcnt(2)" ::: "memory");   // tile 0 landed
  __syncthreads();

  int rbuf = 0, sbuf = 2;
  for (int t = 0; t < NT; ++t) {
    if (t + 2 < NT) STAGE_ATT(t + 2, sbuf);

    const unsigned short* kb_ = smem + rbuf * 8192 + lane * 8;
    // ---- S = Q K^T (kf fragments from shared LDS) ----
    f4v s4[2][4];
    {
      s8v kf[8];
      #pragma unroll
      for (int f = 0; f < 8; ++f) kf[f] = *(const s8v*)(kb_ + f * 512);
      #pragma unroll
      for (int fq = 0; fq < 2; ++fq)
        #pragma unroll
        for (int kt = 0; kt < 4; ++kt) {
          f4v z = {};
          z = __builtin_amdgcn_mfma_f32_16x16x32_bf16(qf[fq][0], kf[kt * 2], z, 0, 0, 0);
          z = __builtin_amdgcn_mfma_f32_16x16x32_bf16(qf[fq][1], kf[kt * 2 + 1], z, 0, 0, 0);
          s4[fq][kt] = z;
        }
    }

    // ---- online softmax: DPP max reduce + defer-max (T13, THR=8 exp2) ----
    #pragma unroll
    for (int fq = 0; fq < 2; ++fq)
      #pragma unroll
      for (int r = 0; r < 4; ++r) {
        float mv = fmaxf(fmaxf(s4[fq][0][r], s4[fq][1][r]),
                         fmaxf(s4[fq][2][r], s4[fq][3][r]));
        mv = max16(mv);
        if (!__all(mv - m_i[fq][r] <= 8.0f)) {
          float mnew = fmaxf(m_i[fq][r], mv);
          float alpha = __builtin_amdgcn_exp2f(m_i[fq][r] - mnew);
          m_i[fq][r] = mnew;
          l_i[fq][r] *= alpha;
          acc[fq][0][r] *= alpha; acc[fq][1][r] *= alpha;
          acc[fq][2][r] *= alpha; acc[fq][3][r] *= alpha;
        }
        float ls = 0.f;
        #pragma unroll
        for (int kt = 0; kt < 4; ++kt) {
          float p = __builtin_amdgcn_exp2f(s4[fq][kt][r] - m_i[fq][r]);
          s4[fq][kt][r] = p;
          ls += p;
        }
        l_i[fq][r] += ls;
      }

    // ---- P -> wave-private LDS, permuted keys (b64 writes) ----
    #pragma unroll
    for (int fq = 0; fq < 2; ++fq)
      #pragma unroll
      for (int r = 0; r < 4; ++r) {
        unsigned int lo = (__float_as_uint(s4[fq][0][r]) >> 16) |
                          (__float_as_uint(s4[fq][1][r]) & 0xffff0000u);
        unsigned int hi = (__float_as_uint(s4[fq][2][r]) >> 16) |
                          (__float_as_uint(s4[fq][3][r]) & 0xffff0000u);
        *(uint2*)(Pw + (fq * 16 + quad * 4 + r) * 72 + l15 * 4) = make_uint2(lo, hi);
      }

    // ---- acc += P V (vf fragments from shared LDS) ----
    {
      const unsigned short* vb_ = smem + rbuf * 8192 + 4096 + lane * 8;
      s8v vf[8];
      #pragma unroll
      for (int f = 0; f < 8; ++f) vf[f] = *(const s8v*)(vb_ + f * 512);
      #pragma unroll
      for (int fq = 0; fq < 2; ++fq) {
        s8v pf0 = *(const s8v*)(Pw + (fq * 16 + l15) * 72 + quad * 8);
        s8v pf1 = *(const s8v*)(Pw + (fq * 16 + l15) * 72 + 32 + quad * 8);
        #pragma unroll
        for (int dt = 0; dt < 4; ++dt) {
          acc[fq][dt] = __builtin_amdgcn_mfma_f32_16x16x32_bf16(pf0, vf[dt * 2], acc[fq][dt], 0, 0, 0);
          acc[fq][dt] = __builtin_amdgcn_mfma_f32_16x16x32_bf16(pf1, vf[dt * 2 + 1], acc[fq][dt], 0, 0, 0);
        }
      }
    }

    if (t + 2 < NT) {
      asm volatile("s_waitcnt vmcnt(2)" ::: "memory");   // tile t+1 landed
    } else if (t + 1 < NT) {
      asm volatile("s_waitcnt vmcnt(0)" ::: "memory");
    }
    __syncthreads();
    rbuf = (rbuf == 2) ? 0 : rbuf + 1;
    sbuf = (sbuf == 2) ? 0 : sbuf + 1;
  }
  #undef STAGE_ATT

  // ---- epilogue ----
  #pragma unroll
  for (int fq = 0; fq < 2; ++fq)
    #pragma unroll
    for (int r = 0; r < 4; ++r) {
      float l = l_i[fq][r];
      #pragma unroll
      for (int msk = 1; msk < 16; msk <<= 1)
        l += __shfl_xor(l, msk, 64);
      float inv = 1.0f / l;
      size_t row = (size_t)(b * NN + n0 + wave * 32 + fq * 16 + quad * 4 + r);
      unsigned short* op = ob + row * CDIM + h * HDIM;
      #pragma unroll
      for (int dt = 0; dt < 4; ++dt)
        op[dt * 16 + l15] = f2bf(acc[fq][dt][r] * inv);
    }
}

// ---------------------------------------------------------------------------
extern "C" void kernel_launch(void* const* d_in, const int* in_sizes, int n_in,
                              void* d_out, int out_size, void* d_ws, size_t ws_size,
                              hipStream_t stream) {
  const float* x    = (const float*)d_in[0];
  const float* temb = (const float*)d_in[1];
  const float* n1g  = (const float*)d_in[2];
  const float* n1b  = (const float*)d_in[3];
  const float* Wq   = (const float*)d_in[4];
  const float* Wk   = (const float*)d_in[5];
  const float* Wv   = (const float*)d_in[6];
  const float* Wo   = (const float*)d_in[7];
  const float* n2g  = (const float*)d_in[8];
  const float* n2b  = (const float*)d_in[9];
  const float* W1   = (const float*)d_in[10];
  const float* W2   = (const float*)d_in[11];
  const float* adaW = (const float*)d_in[12];
  const float* adab = (const float*)d_in[13];
  float* out = (float*)d_out;

  const size_t TOK = (size_t)BB * NN * CDIM;   // 4,194,304
  float* wsf = (float*)d_ws;
  float* mod     = wsf;                                    // 16384 f32
  float* modpart = wsf + 16384;                            // 16*2*6144 f32
  unsigned short* tokb  = (unsigned short*)(wsf + 16384 + MSPLIT * BB * MODC);
  unsigned short* qb    = tokb + TOK;
  unsigned short* kb    = qb + TOK;
  unsigned short* kpack = kb + TOK;
  unsigned short* vpack = kpack + TOK;
  unsigned short* Wqkvt = vpack + TOK;                     // 3M u16
  unsigned short* Wot   = Wqkvt + 3 * CDIM * CDIM;         // 1M
  unsigned short* W1t   = Wot + CDIM * CDIM;               // 4M
  unsigned short* W2t   = W1t + CDIM * MLPD;               // 4M
  unsigned short* h1b   = W2t + MLPD * CDIM;               // 16.7M u16
  unsigned short* vrow  = h1b;          // staging alias (dead before W1 GEMM)
  float* x1 = (float*)qb;               // fp32 alias over qb+kb (dead after fattn)

  const int M = BB * NN;   // 4096

  mod_part<<<dim3(MODC / 256, BB, MSPLIT), 256, 0, stream>>>(temb, adaW, modpart);
  mod_reduce<<<dim3(BB * MODC / 256), 256, 0, stream>>>(modpart, adab, mod);
  ln_mod_bf16<<<dim3(M), 256, 0, stream>>>(x, n1g, n1b, mod, 0, 1024, tokb);

  wcast_all<<<dim3(12288), 256, 0, stream>>>(
      Wq, Wk, Wv, Wo, W1, W2, Wqkvt, Wot, W1t, W2t);

  // fused QKV -> q,k,v row-major bf16
  mfma_gemm_big<<<dim3(24, 32), 1024, 0, stream>>>(
      tokb, Wqkvt, M, 3 * CDIM, CDIM, qb, kb, vrow, 0);

  rope_qk<<<dim3(M, 2), 256, 0, stream>>>(qb, kb, kpack, 0.125f * LOG2E);

  vtrans_pack<<<dim3(NN / 64, BB * HEADS), 256, 0, stream>>>(vrow, vpack);

  fattn_pack<<<dim3((NN / 256) * BB * HEADS), 512, 0, stream>>>(
      qb, kpack, vpack, tokb);

  // x1 = x + gate_msa * (attn @ Wo)
  mfma_gemm_res<<<dim3(CDIM / 128, M / 128), 1024, 0, stream>>>(
      tokb, Wot, M, CDIM, CDIM, x1, x, mod, 2048);

  ln_mod_bf16<<<dim3(M), 256, 0, stream>>>(x1, n2g, n2b, mod, 3072, 4096, tokb);

  // h1 = gelu(xn2 @ W1)
  mfma_gemm_big<<<dim3(MLPD / 128, M / 128), 1024, 0, stream>>>(
      tokb, W1t, M, MLPD, CDIM, h1b, nullptr, nullptr, 1);

  // out = x1 + gate_mlp * (h1 @ W2)
  mfma_gemm_res<<<dim3(CDIM / 128, M / 128), 1024, 0, stream>>>(
      h1b, W2t, M, CDIM, MLPD, out, x1, mod, 5120);
}

// Round 14
// 388.088 us; speedup vs baseline: 1.1064x; 1.0895x over previous
//
#include <hip/hip_runtime.h>
#include <math.h>

#define BB    2
#define NN    2048
#define CDIM  1024
#define HEADS 16
#define HDIM  64
#define MLPD  4096
#define MODC  6144
#define EPSV  1e-5f
#define LOG2E 1.4426950408889634f
#define MSPLIT 16

typedef __attribute__((ext_vector_type(8))) short s8v;     // 8 bf16 (4 VGPRs)
typedef __attribute__((ext_vector_type(4))) float f4v;     // MFMA C/D

__device__ inline unsigned short f2bf(float f) {
  union { float f; unsigned u; } v; v.f = f;
  unsigned r = v.u + 0x7FFFu + ((v.u >> 16) & 1u);   // RNE
  return (unsigned short)(r >> 16);
}
__device__ inline float bf2f(unsigned short h) {
  union { unsigned u; float f; } v; v.u = ((unsigned)h) << 16;
  return v.f;
}

// DPP 16-lane max reduce: VALU-only (no ds_swizzle -> keeps the DS pipe free).
template<int CTRL>
__device__ __forceinline__ float dpp_max_step(float v) {
  int iv = __float_as_int(v);
  int sh = __builtin_amdgcn_update_dpp(iv, iv, CTRL, 0xF, 0xF, false);
  return fmaxf(v, __int_as_float(sh));
}
__device__ __forceinline__ float max16(float v) {
  v = dpp_max_step<0xB1>(v);    // quad_perm [1,0,3,2]  (xor 1)
  v = dpp_max_step<0x4E>(v);    // quad_perm [2,3,0,1]  (xor 2)
  v = dpp_max_step<0x124>(v);   // row_ror:4
  v = dpp_max_step<0x128>(v);   // row_ror:8
  return v;
}

// ---------------------------------------------------------------------------
// K1a: split-K partials for mod = silu(t_emb) @ ada_W
// ---------------------------------------------------------------------------
__global__ __launch_bounds__(256) void mod_part(
    const float* __restrict__ t_emb, const float* __restrict__ ada_W,
    float* __restrict__ part) {
  int j = blockIdx.x * 256 + threadIdx.x;
  int b = blockIdx.y, ks = blockIdx.z;
  __shared__ float st[64];
  if (threadIdx.x < 64) {
    float v = t_emb[b * CDIM + ks * 64 + threadIdx.x];
    st[threadIdx.x] = v / (1.0f + expf(-v));
  }
  __syncthreads();
  float acc = 0.f;
  const float* wp = ada_W + (size_t)(ks * 64) * MODC + j;
  #pragma unroll 8
  for (int i = 0; i < 64; ++i) acc += st[i] * wp[(size_t)i * MODC];
  part[((size_t)ks * BB + b) * MODC + j] = acc;
}

// K1b: reduce partials + bias
__global__ __launch_bounds__(256) void mod_reduce(
    const float* __restrict__ part, const float* __restrict__ ada_b,
    float* __restrict__ mod) {
  int idx = blockIdx.x * 256 + threadIdx.x;   // 0 .. B*MODC-1
  int b = idx / MODC, j = idx % MODC;
  float a = ada_b[j];
  #pragma unroll
  for (int s = 0; s < MSPLIT; ++s) a += part[((size_t)s * BB + b) * MODC + j];
  mod[(size_t)b * MODC + j] = a;
}

// ---------------------------------------------------------------------------
// K2: LN + adaLN modulation, bf16 output
// ---------------------------------------------------------------------------
__device__ inline float wave_sum64(float v) {
  for (int o = 32; o > 0; o >>= 1) v += __shfl_down(v, o, 64);
  return v;
}

__global__ __launch_bounds__(256) void ln_mod_bf16(
    const float* __restrict__ x, const float* __restrict__ g,
    const float* __restrict__ bta, const float* __restrict__ mod,
    int shift_off, int scale_off, unsigned short* __restrict__ out) {
  int r = blockIdx.x;
  int b = r / NN;
  int t = threadIdx.x;
  const float* xr = x + (size_t)r * CDIM;
  float4 xv = ((const float4*)xr)[t];
  float s  = xv.x + xv.y + xv.z + xv.w;
  float s2 = xv.x*xv.x + xv.y*xv.y + xv.z*xv.z + xv.w*xv.w;
  __shared__ float ws1[4], ws2[4];
  float sw = wave_sum64(s), s2w = wave_sum64(s2);
  int lane = t & 63, wid = t >> 6;
  if (lane == 0) { ws1[wid] = sw; ws2[wid] = s2w; }
  __syncthreads();
  float mu  = (ws1[0] + ws1[1] + ws1[2] + ws1[3]) * (1.0f / CDIM);
  float var = (ws2[0] + ws2[1] + ws2[2] + ws2[3]) * (1.0f / CDIM) - mu * mu;
  float rstd = rsqrtf(var + EPSV);
  const float* mods = mod + (size_t)b * MODC;
  float4 gv = ((const float4*)g)[t];
  float4 bv = ((const float4*)bta)[t];
  float4 sc = ((const float4*)(mods + scale_off))[t];
  float4 sh = ((const float4*)(mods + shift_off))[t];
  ushort4 ov;
  ov.x = f2bf(((xv.x - mu) * rstd * gv.x + bv.x) * (1.0f + sc.x) + sh.x);
  ov.y = f2bf(((xv.y - mu) * rstd * gv.y + bv.y) * (1.0f + sc.y) + sh.y);
  ov.z = f2bf(((xv.z - mu) * rstd * gv.z + bv.z) * (1.0f + sc.z) + sh.z);
  ov.w = f2bf(((xv.w - mu) * rstd * gv.w + bv.w) * (1.0f + sc.w) + sh.w);
  ((ushort4*)(out + (size_t)r * CDIM))[t] = ov;
}

// ---------------------------------------------------------------------------
// K3: ALL weight transpose-casts in one launch.  W[K][N] f32 -> Wt[N][K] bf16
// ---------------------------------------------------------------------------
__global__ __launch_bounds__(256) void wcast_all(
    const float* __restrict__ Wq, const float* __restrict__ Wk,
    const float* __restrict__ Wv, const float* __restrict__ Wo,
    const float* __restrict__ W1, const float* __restrict__ W2,
    unsigned short* __restrict__ Wqkvt, unsigned short* __restrict__ Wot,
    unsigned short* __restrict__ W1t, unsigned short* __restrict__ W2t) {
  int bid = blockIdx.x;
  const float* W; unsigned short* Wt; int K, N, t;
  if (bid < 4096) {
    int m = bid >> 10;
    t = bid & 1023;
    K = CDIM; N = CDIM;
    W  = (m == 0) ? Wq : (m == 1) ? Wk : (m == 2) ? Wv : Wo;
    Wt = (m == 3) ? Wot : (Wqkvt + (size_t)m * CDIM * CDIM);
  } else if (bid < 8192) {
    t = bid - 4096; K = CDIM; N = MLPD; W = W1; Wt = W1t;
  } else {
    t = bid - 8192; K = MLPD; N = CDIM; W = W2; Wt = W2t;
  }
  int ntiles = N >> 5;
  int n0 = (t % ntiles) * 32, k0 = (t / ntiles) * 32;
  __shared__ float tile[32][33];
  int tx = threadIdx.x & 31, ty = threadIdx.x >> 5;
  #pragma unroll
  for (int p = 0; p < 4; ++p)
    tile[ty + p * 8][tx] = W[(size_t)(k0 + ty + p * 8) * N + n0 + tx];
  __syncthreads();
  #pragma unroll
  for (int p = 0; p < 4; ++p)
    Wt[(size_t)(n0 + ty + p * 8) * K + k0 + tx] = f2bf(tile[tx][ty + p * 8]);
}

// ---------------------------------------------------------------------------
// K4 v4: bf16 MFMA GEMM, 256x256 tile, 1024 threads = 16 waves (4x4 wave
// grid, each wave owns a 64x64 output), BK=64, NO K-split.
// R13 diagnosis: the 16-wave K-split 128-tile kernel was DS-pipe-bound
// (192 ds_read_b128/CU-iter = 82% of the shared DS pipe; 1.33 MFMA/read).
// This layout: af[4] x bf[4] -> 16 MFMA per 8 reads = 2.0 MFMA/read
// (-33% DS per FLOP), and the 256-wide tile HALVES total staged bytes.
// Same verified XOR-swizzle staging math as mfma_gemm_res (row&7 == l15&7
// on read, lane>>3 on write).  Double-buffered, 128 KB LDS, 1 block/CU.
// Epilogues: mode 0 = QKV 3-way split; mode 1 = exact GELU bf16.
// ---------------------------------------------------------------------------
__global__ __launch_bounds__(1024) void mfma_gemm_256(
    const unsigned short* __restrict__ A,
    const unsigned short* __restrict__ Bt,
    int M, int N, int K,
    unsigned short* __restrict__ Ob, unsigned short* __restrict__ Ob2,
    unsigned short* __restrict__ Ob3, int mode) {
  __shared__ unsigned short SH[2 * 32768];   // 2 bufs x (A 32KB + B 32KB) = 128 KB
  int tid = threadIdx.x;
  int wave = tid >> 6, lane = tid & 63;
  int quad = lane >> 4, l15 = lane & 15;
  int m0 = blockIdx.y * 256, n0 = blockIdx.x * 256;
  int wr = wave >> 2, wc = wave & 3;   // 4x4 wave grid, 64x64 output each

  f4v acc[4][4] = {};

  int srow = lane >> 3;
  int ksrc = ((lane & 7) ^ (lane >> 3)) << 3;   // pre-swizzled source k offset
  const int nt = K >> 6;

  // wave w stages A rows [16w,16w+16) and B rows [16w,16w+16): 2+2 loads.
  #define STAGE_256(T, BUF)                                                    \
    {                                                                          \
      int k0_ = (T) << 6;                                                      \
      unsigned short* ab = SH + (BUF) * 32768 + wave * 1024;                   \
      _Pragma("unroll")                                                        \
      for (int s = 0; s < 2; ++s) {                                            \
        const unsigned short* ga =                                             \
            A + (size_t)(m0 + 16 * wave + 8 * s + srow) * K + k0_ + ksrc;      \
        __builtin_amdgcn_global_load_lds(                                      \
            (const __attribute__((address_space(1))) unsigned int*)(const void*)ga, \
            (__attribute__((address_space(3))) unsigned int*)(void*)(ab + s * 512), \
            16, 0, 0);                                                         \
        const unsigned short* gb =                                             \
            Bt + (size_t)(n0 + 16 * wave + 8 * s + srow) * K + k0_ + ksrc;     \
        __builtin_amdgcn_global_load_lds(                                      \
            (const __attribute__((address_space(1))) unsigned int*)(const void*)gb, \
            (__attribute__((address_space(3))) unsigned int*)(void*)(ab + 16384 + s * 512), \
            16, 0, 0);                                                         \
      }                                                                        \
    }

  STAGE_256(0, 0);
  asm volatile("s_waitcnt vmcnt(0)" ::: "memory");
  __syncthreads();

  int buf = 0;
  for (int t = 0; t < nt; ++t) {
    if (t + 1 < nt) STAGE_256(t + 1, buf ^ 1);

    const unsigned short* Ab = SH + buf * 32768;
    const unsigned short* Bb = Ab + 16384;
    #pragma unroll
    for (int ks = 0; ks < 2; ++ks) {
      int kx = (ks * 32 + quad * 8) ^ ((l15 & 7) << 3);
      s8v af[4], bf[4];
      #pragma unroll
      for (int i = 0; i < 4; ++i)
        af[i] = *(const s8v*)(Ab + (wr * 64 + i * 16 + l15) * 64 + kx);
      #pragma unroll
      for (int j = 0; j < 4; ++j)
        bf[j] = *(const s8v*)(Bb + (wc * 64 + j * 16 + l15) * 64 + kx);
      #pragma unroll
      for (int i = 0; i < 4; ++i)
        #pragma unroll
        for (int j = 0; j < 4; ++j)
          acc[i][j] = __builtin_amdgcn_mfma_f32_16x16x32_bf16(
              af[i], bf[j], acc[i][j], 0, 0, 0);
    }

    if (t + 1 < nt) {
      asm volatile("s_waitcnt vmcnt(0)" ::: "memory");   // next tile landed
      __syncthreads();
      buf ^= 1;
    }
  }
  #undef STAGE_256

  // ---- epilogue (no cross-wave reduce needed) ----
  #pragma unroll
  for (int i = 0; i < 4; ++i) {
    int rbase = m0 + wr * 64 + i * 16 + quad * 4;
    #pragma unroll
    for (int j = 0; j < 4; ++j) {
      int c = n0 + wc * 64 + j * 16 + l15;
      #pragma unroll
      for (int rg = 0; rg < 4; ++rg) {
        int r = rbase + rg;
        float v = acc[i][j][rg];
        if (mode == 0) {
          unsigned short* dst = (c < 1024) ? Ob : ((c < 2048) ? Ob2 : Ob3);
          dst[(size_t)r * 1024 + (c & 1023)] = f2bf(v);
        } else {
          v = 0.5f * v * (1.0f + erff(v * 0.70710678118f));
          Ob[(size_t)r * N + c] = f2bf(v);
        }
      }
    }
  }
}

// ---------------------------------------------------------------------------
// K4b v3: bf16 MFMA GEMM, 128x128 tile, 1024 threads = 16 waves, intra-block
// K-split.  Epilogue: O0 = res + mod[gate]*acc (fp32 out).
// (kept for Wo/W2: N=1024 makes a 256-wide tile leave 3/4 of CUs idle)
// ---------------------------------------------------------------------------
__global__ __launch_bounds__(1024) void mfma_gemm_res(
    const unsigned short* __restrict__ A,
    const unsigned short* __restrict__ Bt,
    int M, int N, int K,
    float* __restrict__ O0,
    const float* __restrict__ res, const float* __restrict__ mod,
    int gate_off) {
  __shared__ unsigned short SH[3 * 16384];   // 3 bufs x (A 16KB + B 16KB) = 96 KB
  int tid = threadIdx.x;
  int wave = tid >> 6, lane = tid & 63;
  int quad = lane >> 4, l15 = lane & 15;
  int m0 = blockIdx.y * 128, n0 = blockIdx.x * 128;
  int pos = wave & 7;
  int om = pos >> 1, on = pos & 1;   // 32-row x 64-col output sub-tile
  int ks = wave >> 3;                // K-half (32 of 64) of the outer tile

  f4v acc[2][4] = {};

  int srow = lane >> 3;
  int ksrc = ((lane & 7) ^ (lane >> 3)) << 3;   // source k offset (elems)
  const int nt = K >> 6;

  #define STAGE_RES(T, BUF)                                                    \
    {                                                                          \
      int k0_ = (T) << 6;                                                      \
      unsigned short* dsta = SH + (BUF) * 16384 + wave * 512;                  \
      const unsigned short* ga =                                               \
          A + (size_t)(m0 + 8 * wave + srow) * K + k0_ + ksrc;                 \
      __builtin_amdgcn_global_load_lds(                                        \
          (const __attribute__((address_space(1))) unsigned int*)(const void*)ga, \
          (__attribute__((address_space(3))) unsigned int*)(void*)dsta,        \
          16, 0, 0);                                                           \
      const unsigned short* gb =                                               \
          Bt + (size_t)(n0 + 8 * wave + srow) * K + k0_ + ksrc;                \
      __builtin_amdgcn_global_load_lds(                                        \
          (const __attribute__((address_space(1))) unsigned int*)(const void*)gb, \
          (__attribute__((address_space(3))) unsigned int*)(void*)(dsta + 8192), \
          16, 0, 0);                                                           \
    }

  STAGE_RES(0, 0);
  STAGE_RES(1, 1);
  asm volatile("s_waitcnt vmcnt(2)" ::: "memory");   // tile 0 landed
  __syncthreads();

  int kx = (ks * 32 + quad * 8) ^ ((l15 & 7) << 3);

  int rbuf = 0, sbuf = 2;
  for (int t = 0; t < nt; ++t) {
    if (t + 2 < nt) STAGE_RES(t + 2, sbuf);

    const unsigned short* base = SH + rbuf * 16384;
    s8v af[2], bf[4];
    #pragma unroll
    for (int i = 0; i < 2; ++i)
      af[i] = *(const s8v*)(base + (om * 32 + i * 16 + l15) * 64 + kx);
    #pragma unroll
    for (int j = 0; j < 4; ++j)
      bf[j] = *(const s8v*)(base + 8192 + (on * 64 + j * 16 + l15) * 64 + kx);
    #pragma unroll
    for (int i = 0; i < 2; ++i)
      #pragma unroll
      for (int j = 0; j < 4; ++j)
        acc[i][j] = __builtin_amdgcn_mfma_f32_16x16x32_bf16(
            af[i], bf[j], acc[i][j], 0, 0, 0);

    if (t + 2 < nt) {
      asm volatile("s_waitcnt vmcnt(2)" ::: "memory");   // tile t+1 landed
    } else if (t + 1 < nt) {
      asm volatile("s_waitcnt vmcnt(0)" ::: "memory");
    }
    __syncthreads();
    rbuf = (rbuf == 2) ? 0 : rbuf + 1;
    sbuf = (sbuf == 2) ? 0 : sbuf + 1;
  }
  #undef STAGE_RES

  // ---- cross-ks reduce via LDS (pad 36 f32/lane), then fused epilogue ----
  float* red = (float*)SH;
  if (wave >= 8) {
    int rb = (wave - 8) * 2304 + lane * 36;
    #pragma unroll
    for (int i = 0; i < 2; ++i)
      #pragma unroll
      for (int j = 0; j < 4; ++j)
        *(f4v*)(red + rb + (i * 4 + j) * 4) = acc[i][j];
  }
  __syncthreads();
  if (wave < 8) {
    int rb = wave * 2304 + lane * 36;
    #pragma unroll
    for (int i = 0; i < 2; ++i)
      #pragma unroll
      for (int j = 0; j < 4; ++j)
        acc[i][j] += *(const f4v*)(red + rb + (i * 4 + j) * 4);
    #pragma unroll
    for (int i = 0; i < 2; ++i) {
      int rbase = m0 + om * 32 + i * 16 + quad * 4;
      #pragma unroll
      for (int j = 0; j < 4; ++j) {
        int c = n0 + on * 64 + j * 16 + l15;
        #pragma unroll
        for (int rg = 0; rg < 4; ++rg) {
          int r = rbase + rg;
          int bb2 = r >> 11;
          O0[(size_t)r * N + c] =
              res[(size_t)r * N + c] + mod[bb2 * MODC + gate_off + c] * acc[i][j][rg];
        }
      }
    }
  }
}

// ---------------------------------------------------------------------------
// K5: fused RoPE. y=0: q in-place (scaled by 1/8*log2e). y=1: k -> kpack
// ---------------------------------------------------------------------------
__global__ __launch_bounds__(256) void rope_qk(
    unsigned short* __restrict__ qb, const unsigned short* __restrict__ kb,
    unsigned short* __restrict__ kpack, float qscale) {
  int r = blockIdx.x;            // b*N + n
  int b = r / NN, n = r % NN;
  int t = threadIdx.x;
  int isK = blockIdx.y;
  const unsigned short* src = isK ? kb : qb;
  float scale = isK ? 1.0f : qscale;
  __shared__ float row[CDIM];
  __shared__ float csv[32], snv[32];
  if (t < 32) {
    float invf = powf(10000.0f, -(float)t / 32.0f);
    float sn, cs;
    sincosf((float)n * invf, &sn, &cs);
    csv[t] = cs * scale; snv[t] = sn * scale;
  }
  const unsigned short* qr = src + (size_t)r * CDIM;
  ushort4 xv = ((const ushort4*)qr)[t];
  row[t * 4 + 0] = bf2f(xv.x);
  row[t * 4 + 1] = bf2f(xv.y);
  row[t * 4 + 2] = bf2f(xv.z);
  row[t * 4 + 3] = bf2f(xv.w);
  __syncthreads();
  unsigned short o[4];
  int c0 = t * 4;
  #pragma unroll
  for (int q4 = 0; q4 < 4; ++q4) {
    int c = c0 + q4;
    int h = c >> 6, d = c & 63;
    int i = d & 31;
    float rh = (d < 32) ? -row[h * 64 + 2 * d + 1] : row[h * 64 + 2 * (d - 32)];
    o[q4] = f2bf(row[c] * csv[i] + rh * snv[i]);
  }
  if (!isK) {
    ((ushort4*)(qb + (size_t)r * CDIM))[t] = make_ushort4(o[0], o[1], o[2], o[3]);
  } else {
    int h = c0 >> 6, d0 = c0 & 63;
    int half = d0 >> 5, quad = (d0 >> 3) & 3, j0 = d0 & 7;  // j0 in {0,4}
    int bh = b * HEADS + h;
    int tt = n >> 6, kt = (n >> 4) & 3, l15 = n & 15;
    int lane = quad * 16 + l15;
    size_t off = ((((size_t)bh * 32 + tt) * 8 + kt * 2 + half) * 64 + lane) * 8 + j0;
    unsigned int lo = (unsigned)o[0] | ((unsigned)o[1] << 16);
    unsigned int hi = (unsigned)o[2] | ((unsigned)o[3] << 16);
    *(uint2*)(kpack + off) = make_uint2(lo, hi);
  }
}

// ---------------------------------------------------------------------------
// K5b: V pack  vrow[B*N][1024] -> vpack[bh][t][f=dt*2+half][lane][8]
// ---------------------------------------------------------------------------
__global__ __launch_bounds__(256) void vtrans_pack(
    const unsigned short* __restrict__ vrow, unsigned short* __restrict__ vpack) {
  int t = blockIdx.x;
  int bh = blockIdx.y;
  int b = bh >> 4, h = bh & 15;
  __shared__ unsigned short L[64 * 72];     // L[key][d], pad 72
  int tid = threadIdx.x;
  #pragma unroll
  for (int p = 0; p < 2; ++p) {
    int c = tid + p * 256;
    int key = c >> 3, dc = (c & 7) * 8;
    *(s8v*)(L + key * 72 + dc) =
        *(const s8v*)(vrow + (size_t)(b * NN + t * 64 + key) * CDIM + h * HDIM + dc);
  }
  __syncthreads();
  #pragma unroll
  for (int p = 0; p < 2; ++p) {
    int o = tid + p * 256;
    int f = o >> 6, lane = o & 63;
    int dt = f >> 1, half = f & 1, quad = lane >> 4, l15 = lane & 15;
    int d = dt * 16 + l15;
    unsigned short tmp[8];
    #pragma unroll
    for (int j = 0; j < 8; ++j) {
      int key = (j & 3) * 16 + half * 8 + quad * 2 + (j >> 2);
      tmp[j] = L[key * 72 + d];
    }
    *(s8v*)(vpack + ((((size_t)bh * 32 + t) * 8 + f) * 64 + lane) * 8) = *(s8v*)tmp;
  }
}

// ---------------------------------------------------------------------------
// K6 v7: K+V LDS-shared flash attention, DPP max, defer-max, depth-2 counted
// vmcnt staging (R13-measured best: 74.9 us).
// ---------------------------------------------------------------------------
__global__ __launch_bounds__(512) void fattn_pack(
    const unsigned short* __restrict__ qb,     // [B*N][1024] (scaled)
    const unsigned short* __restrict__ kpack,  // [bh][32][8][64][8]
    const unsigned short* __restrict__ vpack,  // [bh][32][8][64][8]
    unsigned short* __restrict__ ob) {         // [B*N][1024]
  int bid = blockIdx.x;
  int qt = bid >> 5, bh = bid & 31;            // bid%8 == bh%8 -> XCD locality
  int b = bh >> 4, h = bh & 15;
  int tid = threadIdx.x;
  int wave = tid >> 6, lane = tid & 63;
  int quad = lane >> 4, l15 = lane & 15;

  // LDS: 3 KV buffers (16KB each: K 8KB | V 8KB) + per-wave P staging
  __shared__ unsigned short smem[3 * 8192 + 8 * 2304];
  unsigned short* Pw = smem + 3 * 8192 + wave * 2304;

  int n0 = qt * 256;
  s8v qf[2][2];
  #pragma unroll
  for (int fq = 0; fq < 2; ++fq) {
    int qrow = n0 + wave * 32 + fq * 16 + l15;
    const unsigned short* qp = qb + (size_t)(b * NN + qrow) * CDIM + h * HDIM;
    qf[fq][0] = *(const s8v*)(qp + quad * 8);
    qf[fq][1] = *(const s8v*)(qp + 32 + quad * 8);
  }

  f4v acc[2][4] = {};
  float m_i[2][4], l_i[2][4];
  #pragma unroll
  for (int fq = 0; fq < 2; ++fq)
    #pragma unroll
    for (int r = 0; r < 4; ++r) { m_i[fq][r] = -1e30f; l_i[fq][r] = 0.f; }

  // per-wave global source: fragment #wave of the K / V tile
  const unsigned short* ksrc = kpack + (size_t)bh * 131072 + wave * 512 + lane * 8;
  const unsigned short* vsrc = vpack + (size_t)bh * 131072 + wave * 512 + lane * 8;

  // stage tile T into buffer BUF (u16 offsets: buf*8192; V at +4096)
  #define STAGE_ATT(T, BUF)                                                    \
    {                                                                          \
      __builtin_amdgcn_global_load_lds(                                        \
          (const __attribute__((address_space(1))) unsigned int*)(const void*)(ksrc + (size_t)(T) * 4096), \
          (__attribute__((address_space(3))) unsigned int*)(void*)(smem + (BUF) * 8192 + wave * 512), \
          16, 0, 0);                                                           \
      __builtin_amdgcn_global_load_lds(                                        \
          (const __attribute__((address_space(1))) unsigned int*)(const void*)(vsrc + (size_t)(T) * 4096), \
          (__attribute__((address_space(3))) unsigned int*)(void*)(smem + (BUF) * 8192 + 4096 + wave * 512), \
          16, 0, 0);                                                           \
    }

  const int NT = NN / 64;
  STAGE_ATT(0, 0);
  STAGE_ATT(1, 1);
  asm volatile("s_waitcnt vmcnt(2)" ::: "memory");   // tile 0 landed
  __syncthreads();

  int rbuf = 0, sbuf = 2;
  for (int t = 0; t < NT; ++t) {
    if (t + 2 < NT) STAGE_ATT(t + 2, sbuf);

    const unsigned short* kb_ = smem + rbuf * 8192 + lane * 8;
    // ---- S = Q K^T (kf fragments from shared LDS) ----
    f4v s4[2][4];
    {
      s8v kf[8];
      #pragma unroll
      for (int f = 0; f < 8; ++f) kf[f] = *(const s8v*)(kb_ + f * 512);
      #pragma unroll
      for (int fq = 0; fq < 2; ++fq)
        #pragma unroll
        for (int kt = 0; kt < 4; ++kt) {
          f4v z = {};
          z = __builtin_amdgcn_mfma_f32_16x16x32_bf16(qf[fq][0], kf[kt * 2], z, 0, 0, 0);
          z = __builtin_amdgcn_mfma_f32_16x16x32_bf16(qf[fq][1], kf[kt * 2 + 1], z, 0, 0, 0);
          s4[fq][kt] = z;
        }
    }

    // ---- online softmax: DPP max reduce + defer-max (T13, THR=8 exp2) ----
    #pragma unroll
    for (int fq = 0; fq < 2; ++fq)
      #pragma unroll
      for (int r = 0; r < 4; ++r) {
        float mv = fmaxf(fmaxf(s4[fq][0][r], s4[fq][1][r]),
                         fmaxf(s4[fq][2][r], s4[fq][3][r]));
        mv = max16(mv);
        if (!__all(mv - m_i[fq][r] <= 8.0f)) {
          float mnew = fmaxf(m_i[fq][r], mv);
          float alpha = __builtin_amdgcn_exp2f(m_i[fq][r] - mnew);
          m_i[fq][r] = mnew;
          l_i[fq][r] *= alpha;
          acc[fq][0][r] *= alpha; acc[fq][1][r] *= alpha;
          acc[fq][2][r] *= alpha; acc[fq][3][r] *= alpha;
        }
        float ls = 0.f;
        #pragma unroll
        for (int kt = 0; kt < 4; ++kt) {
          float p = __builtin_amdgcn_exp2f(s4[fq][kt][r] - m_i[fq][r]);
          s4[fq][kt][r] = p;
          ls += p;
        }
        l_i[fq][r] += ls;
      }

    // ---- P -> wave-private LDS, permuted keys (b64 writes) ----
    #pragma unroll
    for (int fq = 0; fq < 2; ++fq)
      #pragma unroll
      for (int r = 0; r < 4; ++r) {
        unsigned int lo = (__float_as_uint(s4[fq][0][r]) >> 16) |
                          (__float_as_uint(s4[fq][1][r]) & 0xffff0000u);
        unsigned int hi = (__float_as_uint(s4[fq][2][r]) >> 16) |
                          (__float_as_uint(s4[fq][3][r]) & 0xffff0000u);
        *(uint2*)(Pw + (fq * 16 + quad * 4 + r) * 72 + l15 * 4) = make_uint2(lo, hi);
      }

    // ---- acc += P V (vf fragments from shared LDS) ----
    {
      const unsigned short* vb_ = smem + rbuf * 8192 + 4096 + lane * 8;
      s8v vf[8];
      #pragma unroll
      for (int f = 0; f < 8; ++f) vf[f] = *(const s8v*)(vb_ + f * 512);
      #pragma unroll
      for (int fq = 0; fq < 2; ++fq) {
        s8v pf0 = *(const s8v*)(Pw + (fq * 16 + l15) * 72 + quad * 8);
        s8v pf1 = *(const s8v*)(Pw + (fq * 16 + l15) * 72 + 32 + quad * 8);
        #pragma unroll
        for (int dt = 0; dt < 4; ++dt) {
          acc[fq][dt] = __builtin_amdgcn_mfma_f32_16x16x32_bf16(pf0, vf[dt * 2], acc[fq][dt], 0, 0, 0);
          acc[fq][dt] = __builtin_amdgcn_mfma_f32_16x16x32_bf16(pf1, vf[dt * 2 + 1], acc[fq][dt], 0, 0, 0);
        }
      }
    }

    if (t + 2 < NT) {
      asm volatile("s_waitcnt vmcnt(2)" ::: "memory");   // tile t+1 landed
    } else if (t + 1 < NT) {
      asm volatile("s_waitcnt vmcnt(0)" ::: "memory");
    }
    __syncthreads();
    rbuf = (rbuf == 2) ? 0 : rbuf + 1;
    sbuf = (sbuf == 2) ? 0 : sbuf + 1;
  }
  #undef STAGE_ATT

  // ---- epilogue ----
  #pragma unroll
  for (int fq = 0; fq < 2; ++fq)
    #pragma unroll
    for (int r = 0; r < 4; ++r) {
      float l = l_i[fq][r];
      #pragma unroll
      for (int msk = 1; msk < 16; msk <<= 1)
        l += __shfl_xor(l, msk, 64);
      float inv = 1.0f / l;
      size_t row = (size_t)(b * NN + n0 + wave * 32 + fq * 16 + quad * 4 + r);
      unsigned short* op = ob + row * CDIM + h * HDIM;
      #pragma unroll
      for (int dt = 0; dt < 4; ++dt)
        op[dt * 16 + l15] = f2bf(acc[fq][dt][r] * inv);
    }
}

// ---------------------------------------------------------------------------
extern "C" void kernel_launch(void* const* d_in, const int* in_sizes, int n_in,
                              void* d_out, int out_size, void* d_ws, size_t ws_size,
                              hipStream_t stream) {
  const float* x    = (const float*)d_in[0];
  const float* temb = (const float*)d_in[1];
  const float* n1g  = (const float*)d_in[2];
  const float* n1b  = (const float*)d_in[3];
  const float* Wq   = (const float*)d_in[4];
  const float* Wk   = (const float*)d_in[5];
  const float* Wv   = (const float*)d_in[6];
  const float* Wo   = (const float*)d_in[7];
  const float* n2g  = (const float*)d_in[8];
  const float* n2b  = (const float*)d_in[9];
  const float* W1   = (const float*)d_in[10];
  const float* W2   = (const float*)d_in[11];
  const float* adaW = (const float*)d_in[12];
  const float* adab = (const float*)d_in[13];
  float* out = (float*)d_out;

  const size_t TOK = (size_t)BB * NN * CDIM;   // 4,194,304
  float* wsf = (float*)d_ws;
  float* mod     = wsf;                                    // 16384 f32
  float* modpart = wsf + 16384;                            // 16*2*6144 f32
  unsigned short* tokb  = (unsigned short*)(wsf + 16384 + MSPLIT * BB * MODC);
  unsigned short* qb    = tokb + TOK;
  unsigned short* kb    = qb + TOK;
  unsigned short* kpack = kb + TOK;
  unsigned short* vpack = kpack + TOK;
  unsigned short* Wqkvt = vpack + TOK;                     // 3M u16
  unsigned short* Wot   = Wqkvt + 3 * CDIM * CDIM;         // 1M
  unsigned short* W1t   = Wot + CDIM * CDIM;               // 4M
  unsigned short* W2t   = W1t + CDIM * MLPD;               // 4M
  unsigned short* h1b   = W2t + MLPD * CDIM;               // 16.7M u16
  unsigned short* vrow  = h1b;          // staging alias (dead before W1 GEMM)
  float* x1 = (float*)qb;               // fp32 alias over qb+kb (dead after fattn)

  const int M = BB * NN;   // 4096

  mod_part<<<dim3(MODC / 256, BB, MSPLIT), 256, 0, stream>>>(temb, adaW, modpart);
  mod_reduce<<<dim3(BB * MODC / 256), 256, 0, stream>>>(modpart, adab, mod);
  ln_mod_bf16<<<dim3(M), 256, 0, stream>>>(x, n1g, n1b, mod, 0, 1024, tokb);

  wcast_all<<<dim3(12288), 256, 0, stream>>>(
      Wq, Wk, Wv, Wo, W1, W2, Wqkvt, Wot, W1t, W2t);

  // fused QKV -> q,k,v row-major bf16  (256x256 tile, grid 12x16)
  mfma_gemm_256<<<dim3(3 * CDIM / 256, M / 256), 1024, 0, stream>>>(
      tokb, Wqkvt, M, 3 * CDIM, CDIM, qb, kb, vrow, 0);

  rope_qk<<<dim3(M, 2), 256, 0, stream>>>(qb, kb, kpack, 0.125f * LOG2E);

  vtrans_pack<<<dim3(NN / 64, BB * HEADS), 256, 0, stream>>>(vrow, vpack);

  fattn_pack<<<dim3((NN / 256) * BB * HEADS), 512, 0, stream>>>(
      qb, kpack, vpack, tokb);

  // x1 = x + gate_msa * (attn @ Wo)
  mfma_gemm_res<<<dim3(CDIM / 128, M / 128), 1024, 0, stream>>>(
      tokb, Wot, M, CDIM, CDIM, x1, x, mod, 2048);

  ln_mod_bf16<<<dim3(M), 256, 0, stream>>>(x1, n2g, n2b, mod, 3072, 4096, tokb);

  // h1 = gelu(xn2 @ W1)  (256x256 tile, grid 16x16 = 1 block/CU)
  mfma_gemm_256<<<dim3(MLPD / 256, M / 256), 1024, 0, stream>>>(
      tokb, W1t, M, MLPD, CDIM, h1b, nullptr, nullptr, 1);

  // out = x1 + gate_mlp * (h1 @ W2)
  mfma_gemm_res<<<dim3(CDIM / 128, M / 128), 1024, 0, stream>>>(
      h1b, W2t, M, CDIM, MLPD, out, x1, mod, 5120);
}